// Round 11
// baseline (1096.560 us; speedup 1.0000x reference)
//
#include <hip/hip_runtime.h>
#include <cmath>

#define NT 256

// ---- problem constants (DEPTH=18, N_ARY=2, H=128, X=128) ----
#define NTOT   262143     // node count (ids 0..262142)
#define NINT   131071     // internal nodes: ids 0 .. 131070

// ws layout (floats) — identical to rounds 6..10 (proven available)
#define WHC_OFF   0                        // [NINT][128] (bias included)
#define WF_OFF    (NINT * 128)             // [NINT][128] (bias included; b1_128 overwrites with f for lvl>=7)
#define UFT_OFF   (2 * NINT * 128)         // [256][128] f32 (tail)
#define UHCT_OFF  (UFT_OFF + 32768)        // [256][128] f32 (tail)
#define PKWW_OFF  (UHCT_OFF + 32768)       // 24576 slots x 16B bf16 frags
#define PKUF_OFF  (PKWW_OFF + 98304)       // 24576 slots x 16B
#define PKUHC_OFF (PKUF_OFF + 98304)       // 24576 slots x 16B
#define WS_FLOATS (PKUHC_OFF + 98304)
#define WS_BYTES  ((size_t)WS_FLOATS * 4)  // ~135.7 MB

// 6 product blocks p: A-term PA[p], B-term PB[p]
#define PA_PACK 0x120100   // {0,0,1,0,2,1}
#define PB_PACK 0x102010   // {0,1,0,2,0,1}

typedef __attribute__((ext_vector_type(8))) short short8v;
typedef __attribute__((ext_vector_type(4))) float f32x4;

__device__ __forceinline__ float sigmoid_(float v) {
    return 1.0f / (1.0f + expf(-v));
}

// truncation split of fp32 into 3 bf16 terms (exact residuals)
__device__ __forceinline__ void split3(float a, unsigned &t0, unsigned &t1, unsigned &t2) {
    unsigned u0 = __float_as_uint(a) & 0xffff0000u;
    float f0 = __uint_as_float(u0);
    float r1 = a - f0;
    unsigned u1 = __float_as_uint(r1) & 0xffff0000u;
    float f1 = __uint_as_float(u1);
    float r2 = r1 - f1;
    unsigned u2 = __float_as_uint(r2) & 0xffff0000u;
    t0 = u0 >> 16; t1 = u1 >> 16; t2 = u2 >> 16;
}
__device__ __forceinline__ float bf2f(unsigned hbits) {
    return __uint_as_float(hbits << 16);
}

// =================== weight prep (round-6, proven) ===================
__global__ __launch_bounds__(NT) void prep_pack(
    const float* __restrict__ Ww, const float* __restrict__ Uf,
    const float* __restrict__ Uhc, float* __restrict__ ws)
{
    int t = blockIdx.x * NT + threadIdx.x;
    if (t < 32768) { int k = t >> 7, j = t & 127; ws[UFT_OFF + t] = Uf[j * 256 + k]; return; }
    t -= 32768;
    if (t < 32768) { int k = t >> 7, j = t & 127; ws[UHCT_OFF + t] = Uhc[j * 256 + k]; return; }
    t -= 32768;

    const float* src; int term; uint4* dst; int q;
    if (t < 24576) {                       // PKWW
        q = t;
        int l = q & 63, j = (q >> 6) & 15, s = q >> 10;
        int p = s >> 2, ks = s & 3;
        term = (PB_PACK >> (p * 4)) & 3;
        int kb = ks * 32 + (l >> 4) * 8, col = j * 16 + (l & 15);
        src = Ww + col * 128 + kb;
        dst = (uint4*)(ws + PKWW_OFF);
    } else if (t < 49152) {                // PKUF
        q = t - 24576;
        int l = q & 63, j = (q >> 6) & 7, s = q >> 9;
        int p = s >> 3, ks = s & 7;
        term = (PB_PACK >> (p * 4)) & 3;
        int kb = ks * 32 + (l >> 4) * 8, col = j * 16 + (l & 15);
        src = Uf + col * 256 + kb;
        dst = (uint4*)(ws + PKUF_OFF);
    } else if (t < 73728) {                // PKUHC
        q = t - 49152;
        int l = q & 63, j = (q >> 6) & 7, s = q >> 9;
        int p = s >> 3, ks = s & 7;
        term = (PB_PACK >> (p * 4)) & 3;
        int kb = ks * 32 + (l >> 4) * 8, col = j * 16 + (l & 15);
        src = Uhc + col * 256 + kb;
        dst = (uint4*)(ws + PKUHC_OFF);
    } else return;

    unsigned hv[8];
#pragma unroll
    for (int e = 0; e < 8; ++e) {
        unsigned a, b, c; split3(src[e], a, b, c);
        hv[e] = (term == 0) ? a : (term == 1 ? b : c);
    }
    uint4 o;
    o.x = hv[0] | (hv[1] << 16); o.y = hv[2] | (hv[3] << 16);
    o.z = hv[4] | (hv[5] << 16); o.w = hv[6] | (hv[7] << 16);
    dst[q] = o;
}

// stage helpers: 2048 uint4 (32 KB) per chunk, 512 threads, 4 per thread
#define LOADC(srcbase) { const uint4* s_ = (srcbase); \
    nx0 = s_[tid]; nx1 = s_[tid + 512]; nx2 = s_[tid + 1024]; nx3 = s_[tid + 1536]; }
#define WRITEC(dstbase) { uint4* d_ = (dstbase); \
    d_[tid] = nx0; d_[tid + 512] = nx1; d_[tid + 1024] = nx2; d_[tid + 1536] = nx3; }

// =================== wx: 128 nodes/block, 8 waves, wave tile 32x128 ===================
__global__ __launch_bounds__(512) void wx_mfma5(
    const float* __restrict__ x, const float* __restrict__ ws_all,
    const float* __restrict__ Wb, float* __restrict__ ws, float* __restrict__ h)
{
    __shared__ short As[128 * 384];           // 96 KB A-pack (K=128)
    __shared__ uint4 sBb[2][2048];            // 64 KB; reused as leaf-wf stash f32[128][128]
    char* Asb = (char*)As;
    const int tid = threadIdx.x;
    const int nbase = blockIdx.x * 128;
    const uint4* pkb = (const uint4*)(ws_all + PKWW_OFF);

    uint4 nx0, nx1, nx2, nx3;
    LOADC(pkb);                               // chunk 0 -> regs (lands during conversion)

    // ---- convert x tile -> 3-term bf16 A-pack (r10 verbatim) ----
    for (int i = 0; i < 8; ++i) {
        int idx = i * 512 + tid;
        int m = idx >> 5, g = idx & 31;
        int node = nbase + m; if (node > NTOT - 1) node = NTOT - 1;
        float4 v = *(const float4*)(x + (size_t)node * 128 + g * 4);
        unsigned a0[4], a1[4], a2[4];
        split3(v.x, a0[0], a1[0], a2[0]); split3(v.y, a0[1], a1[1], a2[1]);
        split3(v.z, a0[2], a1[2], a2[2]); split3(v.w, a0[3], a1[3], a2[3]);
        int ks = g >> 3, kg = (g >> 1) & 3, hw = (g & 1) * 8;
        int kss = ks ^ ((m >> 2) & 3), kgs = kg ^ (m & 3);
        char* base = Asb + m * 768 + kgs * 16 + hw;
        *(uint2*)(base + ((0 * 4 + kss) << 6)) = make_uint2(a0[0] | (a0[1] << 16), a0[2] | (a0[3] << 16));
        *(uint2*)(base + ((1 * 4 + kss) << 6)) = make_uint2(a1[0] | (a1[1] << 16), a1[2] | (a1[3] << 16));
        *(uint2*)(base + ((2 * 4 + kss) << 6)) = make_uint2(a2[0] | (a2[1] << 16), a2[2] | (a2[3] << 16));
    }
    WRITEC(&sBb[0][0]);
    __syncthreads();

    const int lane = tid & 63, wv = tid >> 6;
    const int li = lane & 15, kg = lane >> 4;
    const int rg = wv & 3, jh = wv >> 2;
    const int mf0 = rg * 32 + li, mf1 = mf0 + 16;
    const int mswz0 = (mf0 >> 2) & 3, mswz1 = (mf1 >> 2) & 3;
    const char* arbase0 = Asb + mf0 * 768 + ((kg ^ (mf0 & 3)) << 4);
    const char* arbase1 = Asb + mf1 * 768 + ((kg ^ (mf1 & 3)) << 4);

    f32x4 acc[2][8];
#pragma unroll
    for (int rt = 0; rt < 2; ++rt)
#pragma unroll
        for (int j = 0; j < 8; ++j) acc[rt][j] = (f32x4){0.f, 0.f, 0.f, 0.f};

    int cur = 0;
#pragma unroll 1
    for (int c = 0; c < 12; ++c) {
        if (c < 11) LOADC(pkb + (c + 1) * 2048);
        const int p = c >> 1, hh = c & 1;
        const int spA = (PA_PACK >> (p * 4)) & 3;
        const short8v* sBs = (const short8v*)&sBb[cur][0];
#pragma unroll
        for (int ks2 = 0; ks2 < 2; ++ks2) {
            int ks = hh * 2 + ks2;
            short8v a0 = *(const short8v*)(arbase0 + ((spA * 4 + (ks ^ mswz0)) << 6));
            short8v a1 = *(const short8v*)(arbase1 + ((spA * 4 + (ks ^ mswz1)) << 6));
#pragma unroll
            for (int jj = 0; jj < 8; ++jj) {
                short8v b = sBs[(ks2 * 16 + jh * 8 + jj) * 64 + lane];
                acc[0][jj] = __builtin_amdgcn_mfma_f32_16x16x32_bf16(a0, b, acc[0][jj], 0, 0, 0);
                acc[1][jj] = __builtin_amdgcn_mfma_f32_16x16x32_bf16(a1, b, acc[1][jj], 0, 0, 0);
            }
        }
        if (c < 11) WRITEC(&sBb[cur ^ 1][0]);
        __syncthreads();
        cur ^= 1;
    }

    // ---- epilogue: jh=0 owns cols 0..127 (hc), jh=1 owns cols 128..255 (wf) ----
    float* whcw = ws + WHC_OFF;
    float* wfw  = ws + WF_OFF;
    float* sF = (float*)&sBb[0][0];           // 128 x 128 f32 stash
    // stash wf-half (+bias) for leaf fusion
    if (jh == 1) {
#pragma unroll
        for (int rt = 0; rt < 2; ++rt)
#pragma unroll
            for (int jj = 0; jj < 8; ++jj) {
                int colr = jj * 16 + li;          // relative col in wf half
                float bia = Wb[128 + colr];
#pragma unroll
                for (int r = 0; r < 4; ++r) {
                    int row = rg * 32 + rt * 16 + kg * 4 + r;
                    sF[row * 128 + colr] = acc[rt][jj][r] + bia;
                }
            }
    }
    __syncthreads();

#pragma unroll
    for (int rt = 0; rt < 2; ++rt)
#pragma unroll
        for (int r = 0; r < 4; ++r) {
            int row = rg * 32 + rt * 16 + kg * 4 + r;
            int node = nbase + row;
            if (node >= NTOT) continue;
            if (node < NINT) {
                if (jh == 0) {
#pragma unroll
                    for (int jj = 0; jj < 8; ++jj) {
                        int col = jj * 16 + li;
                        whcw[(size_t)node * 128 + col] = acc[rt][jj][r] + Wb[col];
                    }
                } else {
#pragma unroll
                    for (int jj = 0; jj < 8; ++jj) {
                        int col = jj * 16 + li;
                        wfw[(size_t)node * 128 + col] = acc[rt][jj][r] + Wb[128 + col];
                    }
                }
            } else if (jh == 0) {
#pragma unroll
                for (int jj = 0; jj < 8; ++jj) {
                    int col = jj * 16 + li;
                    float hc = acc[rt][jj][r] + Wb[col];
                    float f = sigmoid_(sF[row * 128 + col]);
                    h[(size_t)node * 128 + col] = (1.0f - f) * tanhf(hc);
                }
            }
        }
}

// =================== level pass 1: f = sigmoid(hcat@UfT + wf) -> overwrite wf ===================
// 128 parents/block, 8 waves, wave tile 32x64; K=256 as two K=128 halves (A-pack rebuilt per half).
__global__ __launch_bounds__(512) void b1_128(
    const float* __restrict__ ws_all, float* __restrict__ ws,
    const float* __restrict__ h, int start)
{
    __shared__ short As[128 * 384];           // 96 KB (K=128 half-pack)
    __shared__ uint4 sBb[2][2048];            // 64 KB
    char* Asb = (char*)As;
    const int tid = threadIdx.x;
    const int s0 = start + blockIdx.x * 128;
    const uint4* ufpk = (const uint4*)(ws_all + PKUF_OFF);
    float* wfw = ws + WF_OFF;

    const int lane = tid & 63, wv = tid >> 6;
    const int li = lane & 15, kg = lane >> 4;
    const int rg = wv & 3, jh = wv >> 2;
    const int mf0 = rg * 32 + li, mf1 = mf0 + 16;
    const int mswz0 = (mf0 >> 2) & 3, mswz1 = (mf1 >> 2) & 3;
    const char* arbase0 = Asb + mf0 * 768 + ((kg ^ (mf0 & 3)) << 4);
    const char* arbase1 = Asb + mf1 * 768 + ((kg ^ (mf1 & 3)) << 4);

    f32x4 acc[2][4];
#pragma unroll
    for (int rt = 0; rt < 2; ++rt)
#pragma unroll
        for (int j = 0; j < 4; ++j) acc[rt][j] = (f32x4){0.f, 0.f, 0.f, 0.f};

    uint4 nx0, nx1, nx2, nx3;
    int cur = 0;
#pragma unroll 1
    for (int half = 0; half < 2; ++half) {
        LOADC(ufpk + (size_t)(half * 4) * 512);   // p=0 chunk of this half
        __syncthreads();                          // prior A-pack reads done
        // conv: A-pack from child h rows (k-half = one child per m)
        for (int i = 0; i < 8; ++i) {
            int idx = i * 512 + tid;
            int m = idx >> 5, g = idx & 31;
            int cn = 2 * (s0 + m) + 1 + half;
            float4 v = *(const float4*)(h + (size_t)cn * 128 + g * 4);
            unsigned a0[4], a1[4], a2[4];
            split3(v.x, a0[0], a1[0], a2[0]); split3(v.y, a0[1], a1[1], a2[1]);
            split3(v.z, a0[2], a1[2], a2[2]); split3(v.w, a0[3], a1[3], a2[3]);
            int ks = g >> 3, kgr = (g >> 1) & 3, hw = (g & 1) * 8;
            int kss = ks ^ ((m >> 2) & 3), kgs = kgr ^ (m & 3);
            char* base = Asb + m * 768 + kgs * 16 + hw;
            *(uint2*)(base + ((0 * 4 + kss) << 6)) = make_uint2(a0[0] | (a0[1] << 16), a0[2] | (a0[3] << 16));
            *(uint2*)(base + ((1 * 4 + kss) << 6)) = make_uint2(a1[0] | (a1[1] << 16), a1[2] | (a1[3] << 16));
            *(uint2*)(base + ((2 * 4 + kss) << 6)) = make_uint2(a2[0] | (a2[1] << 16), a2[2] | (a2[3] << 16));
        }
        WRITEC(&sBb[cur][0]);
        __syncthreads();
#pragma unroll 1
        for (int p = 0; p < 6; ++p) {
            if (p < 5) LOADC(ufpk + (size_t)((p + 1) * 8 + half * 4) * 512);
            const int spA = (PA_PACK >> (p * 4)) & 3;
            const short8v* sBs = (const short8v*)&sBb[cur][0];
#pragma unroll
            for (int ks = 0; ks < 4; ++ks) {
                short8v a0 = *(const short8v*)(arbase0 + ((spA * 4 + (ks ^ mswz0)) << 6));
                short8v a1 = *(const short8v*)(arbase1 + ((spA * 4 + (ks ^ mswz1)) << 6));
#pragma unroll
                for (int jj = 0; jj < 4; ++jj) {
                    short8v b = sBs[(ks * 8 + jh * 4 + jj) * 64 + lane];
                    acc[0][jj] = __builtin_amdgcn_mfma_f32_16x16x32_bf16(a0, b, acc[0][jj], 0, 0, 0);
                    acc[1][jj] = __builtin_amdgcn_mfma_f32_16x16x32_bf16(a1, b, acc[1][jj], 0, 0, 0);
                }
            }
            if (p < 5) WRITEC(&sBb[cur ^ 1][0]);
            __syncthreads();
            cur ^= 1;
        }
    }

    // epilogue: f = sigmoid(acc + wf) -> overwrite wf slot
#pragma unroll
    for (int rt = 0; rt < 2; ++rt)
#pragma unroll
        for (int jj = 0; jj < 4; ++jj) {
            int col = jh * 64 + jj * 16 + li;
#pragma unroll
            for (int r = 0; r < 4; ++r) {
                size_t gn = (size_t)(s0 + rg * 32 + rt * 16 + kg * 4 + r);
                float wf = wfw[gn * 128 + col];
                wfw[gn * 128 + col] = sigmoid_(acc[rt][jj][r] + wf);
            }
        }
}

// =================== level pass 2: cand = (f_rep*hcat)@UhcT + epilogue ===================
__global__ __launch_bounds__(512) void b2_128(
    const float* __restrict__ ws_all, float* __restrict__ h, int start)
{
    __shared__ short As[128 * 384];
    __shared__ uint4 sBb[2][2048];
    char* Asb = (char*)As;
    const int tid = threadIdx.x;
    const int s0 = start + blockIdx.x * 128;
    const uint4* uhcpk = (const uint4*)(ws_all + PKUHC_OFF);
    const float* fw   = ws_all + WF_OFF;      // holds f (written by b1_128)
    const float* whcw = ws_all + WHC_OFF;

    const int lane = tid & 63, wv = tid >> 6;
    const int li = lane & 15, kg = lane >> 4;
    const int rg = wv & 3, jh = wv >> 2;
    const int mf0 = rg * 32 + li, mf1 = mf0 + 16;
    const int mswz0 = (mf0 >> 2) & 3, mswz1 = (mf1 >> 2) & 3;
    const char* arbase0 = Asb + mf0 * 768 + ((kg ^ (mf0 & 3)) << 4);
    const char* arbase1 = Asb + mf1 * 768 + ((kg ^ (mf1 & 3)) << 4);

    f32x4 acc[2][4];
#pragma unroll
    for (int rt = 0; rt < 2; ++rt)
#pragma unroll
        for (int j = 0; j < 4; ++j) acc[rt][j] = (f32x4){0.f, 0.f, 0.f, 0.f};

    uint4 nx0, nx1, nx2, nx3;
    int cur = 0;
#pragma unroll 1
    for (int half = 0; half < 2; ++half) {
        LOADC(uhcpk + (size_t)(half * 4) * 512);
        __syncthreads();
        // conv with f-scale: A = split3(f[m][k&127] * hcat[m][k])
        for (int i = 0; i < 8; ++i) {
            int idx = i * 512 + tid;
            int m = idx >> 5, g = idx & 31;
            int cn = 2 * (s0 + m) + 1 + half;
            float4 v = *(const float4*)(h + (size_t)cn * 128 + g * 4);
            float4 f4 = *(const float4*)(fw + (size_t)(s0 + m) * 128 + g * 4);
            v.x *= f4.x; v.y *= f4.y; v.z *= f4.z; v.w *= f4.w;
            unsigned a0[4], a1[4], a2[4];
            split3(v.x, a0[0], a1[0], a2[0]); split3(v.y, a0[1], a1[1], a2[1]);
            split3(v.z, a0[2], a1[2], a2[2]); split3(v.w, a0[3], a1[3], a2[3]);
            int ks = g >> 3, kgr = (g >> 1) & 3, hw = (g & 1) * 8;
            int kss = ks ^ ((m >> 2) & 3), kgs = kgr ^ (m & 3);
            char* base = Asb + m * 768 + kgs * 16 + hw;
            *(uint2*)(base + ((0 * 4 + kss) << 6)) = make_uint2(a0[0] | (a0[1] << 16), a0[2] | (a0[3] << 16));
            *(uint2*)(base + ((1 * 4 + kss) << 6)) = make_uint2(a1[0] | (a1[1] << 16), a1[2] | (a1[3] << 16));
            *(uint2*)(base + ((2 * 4 + kss) << 6)) = make_uint2(a2[0] | (a2[1] << 16), a2[2] | (a2[3] << 16));
        }
        WRITEC(&sBb[cur][0]);
        __syncthreads();
#pragma unroll 1
        for (int p = 0; p < 6; ++p) {
            if (p < 5) LOADC(uhcpk + (size_t)((p + 1) * 8 + half * 4) * 512);
            const int spA = (PA_PACK >> (p * 4)) & 3;
            const short8v* sBs = (const short8v*)&sBb[cur][0];
#pragma unroll
            for (int ks = 0; ks < 4; ++ks) {
                short8v a0 = *(const short8v*)(arbase0 + ((spA * 4 + (ks ^ mswz0)) << 6));
                short8v a1 = *(const short8v*)(arbase1 + ((spA * 4 + (ks ^ mswz1)) << 6));
#pragma unroll
                for (int jj = 0; jj < 4; ++jj) {
                    short8v b = sBs[(ks * 8 + jh * 4 + jj) * 64 + lane];
                    acc[0][jj] = __builtin_amdgcn_mfma_f32_16x16x32_bf16(a0, b, acc[0][jj], 0, 0, 0);
                    acc[1][jj] = __builtin_amdgcn_mfma_f32_16x16x32_bf16(a1, b, acc[1][jj], 0, 0, 0);
                }
            }
            if (p < 5) WRITEC(&sBb[cur ^ 1][0]);
            __syncthreads();
            cur ^= 1;
        }
    }

    // epilogue: h = f*(c1+c2) + (1-f)*tanh(cand + whc)
#pragma unroll
    for (int rt = 0; rt < 2; ++rt)
#pragma unroll
        for (int jj = 0; jj < 4; ++jj) {
            int col = jh * 64 + jj * 16 + li;
#pragma unroll
            for (int r = 0; r < 4; ++r) {
                size_t gn = (size_t)(s0 + rg * 32 + rt * 16 + kg * 4 + r);
                float f = fw[gn * 128 + col];
                float whcv = whcw[gn * 128 + col];
                float c1 = h[(2 * gn + 1) * 128 + col];
                float c2 = h[(2 * gn + 2) * 128 + col];
                float t = tanhf(acc[rt][jj][r] + whcv);
                h[gn * 128 + col] = f * (c1 + c2) + (1.0f - f) * t;
            }
        }
}

// =================== fused 64-node level kernel (r10, proven) — level 6 only ===================
__global__ __launch_bounds__(512) void lvl_fused(
    const float* __restrict__ ws_all, float* __restrict__ h, int start)
{
    __shared__ short As[64 * 768];            // 96 KB
    __shared__ uint4 sBb[2][2048];            // 2 x 32 KB
    char* Asb = (char*)As;
    float* f_lds = (float*)&sBb[0][0];
    const int tid = threadIdx.x;
    const int s0 = start + blockIdx.x * 64;
    const float* hbase = h + ((size_t)2 * s0 + 1) * 128;
    const uint4* ufpk  = (const uint4*)(ws_all + PKUF_OFF);
    const uint4* uhcpk = (const uint4*)(ws_all + PKUHC_OFF);
    const float* wfw   = ws_all + WF_OFF;
    const float* whcw  = ws_all + WHC_OFF;

    uint4 nx0, nx1, nx2, nx3;
    LOADC(ufpk);

    for (int i = 0; i < 8; ++i) {
        int idx = i * 512 + tid;
        int m = idx >> 6, g = idx & 63;
        float4 v = *(const float4*)(hbase + m * 256 + g * 4);
        unsigned a0[4], a1[4], a2[4];
        split3(v.x, a0[0], a1[0], a2[0]); split3(v.y, a0[1], a1[1], a2[1]);
        split3(v.z, a0[2], a1[2], a2[2]); split3(v.w, a0[3], a1[3], a2[3]);
        int ks = g >> 3, kg = (g >> 1) & 3, hw = (g & 1) * 8;
        int kss = ks ^ ((m >> 2) & 7), kgs = kg ^ (m & 3);
        char* base = Asb + m * 1536 + kgs * 16 + hw;
        *(uint2*)(base + ((0 * 8 + kss) << 6)) = make_uint2(a0[0] | (a0[1] << 16), a0[2] | (a0[3] << 16));
        *(uint2*)(base + ((1 * 8 + kss) << 6)) = make_uint2(a1[0] | (a1[1] << 16), a1[2] | (a1[3] << 16));
        *(uint2*)(base + ((2 * 8 + kss) << 6)) = make_uint2(a2[0] | (a2[1] << 16), a2[2] | (a2[3] << 16));
    }
    WRITEC(&sBb[0][0]);
    __syncthreads();

    const int lane = tid & 63, wv = tid >> 6;
    const int li = lane & 15, kg = lane >> 4;
    const int rt = wv & 3, jh = wv >> 2;
    const int mf = rt * 16 + li;
    const int mswz = (mf >> 2) & 7;
    const char* arbase = Asb + mf * 1536 + ((kg ^ (mf & 3)) << 4);
    const int rbase = rt * 16 + kg * 4;

    f32x4 acc[4];
#pragma unroll
    for (int j = 0; j < 4; ++j) acc[j] = (f32x4){0.f, 0.f, 0.f, 0.f};

    int cur = 0;
#pragma unroll 1
    for (int c = 0; c < 12; ++c) {
        if (c < 11) LOADC(ufpk + (c + 1) * 2048);
        const int p = c >> 1, hh = c & 1;
        const int spA = (PA_PACK >> (p * 4)) & 3;
        const short8v* sBs = (const short8v*)&sBb[cur][0];
#pragma unroll
        for (int ks2 = 0; ks2 < 4; ++ks2) {
            int ks = hh * 4 + ks2;
            short8v a = *(const short8v*)(arbase + ((spA * 8 + (ks ^ mswz)) << 6));
#pragma unroll
            for (int jj = 0; jj < 4; ++jj)
                acc[jj] = __builtin_amdgcn_mfma_f32_16x16x32_bf16(a, sBs[(ks2 * 8 + jh * 4 + jj) * 64 + lane], acc[jj], 0, 0, 0);
        }
        if (c < 11) WRITEC(&sBb[cur ^ 1][0]);
        __syncthreads();
        cur ^= 1;
    }
    float freg[4][4];
#pragma unroll
    for (int jj = 0; jj < 4; ++jj)
#pragma unroll
        for (int r = 0; r < 4; ++r) {
            int col = (jh * 4 + jj) * 16 + li;
            size_t gn = (size_t)(s0 + rbase + r);
            float f = sigmoid_(acc[jj][r] + wfw[gn * 128 + col]);
            freg[jj][r] = f;
            f_lds[(rbase + r) * 128 + col] = f;
        }
    __syncthreads();

    LOADC(uhcpk);
    for (int i = 0; i < 4; ++i) {
        int idx = i * 512 + tid;
        int kgr = idx & 3, ksr = (idx >> 2) & 7, m = idx >> 5;
        int kss = ksr ^ ((m >> 2) & 7);
        int kgs = kgr ^ (m & 3);
        char* base = Asb + m * 1536 + (kgs << 4);
        uint4 g0 = *(uint4*)(base + ((0 * 8 + kss) << 6));
        uint4 g1 = *(uint4*)(base + ((1 * 8 + kss) << 6));
        uint4 g2 = *(uint4*)(base + ((2 * 8 + kss) << 6));
        unsigned w0[4] = {g0.x, g0.y, g0.z, g0.w};
        unsigned w1[4] = {g1.x, g1.y, g1.z, g1.w};
        unsigned w2[4] = {g2.x, g2.y, g2.z, g2.w};
        unsigned o0[4] = {0, 0, 0, 0}, o1[4] = {0, 0, 0, 0}, o2[4] = {0, 0, 0, 0};
#pragma unroll
        for (int e = 0; e < 8; ++e) {
            unsigned h0 = (e & 1) ? (w0[e >> 1] >> 16) : (w0[e >> 1] & 0xffffu);
            unsigned h1 = (e & 1) ? (w1[e >> 1] >> 16) : (w1[e >> 1] & 0xffffu);
            unsigned h2 = (e & 1) ? (w2[e >> 1] >> 16) : (w2[e >> 1] & 0xffffu);
            float a = bf2f(h0) + bf2f(h1) + bf2f(h2);
            int kph = ksr * 32 + kgr * 8 + e;
            float pv = a * f_lds[m * 128 + (kph & 127)];
            unsigned s0_, s1_, s2_; split3(pv, s0_, s1_, s2_);
            o0[e >> 1] |= s0_ << ((e & 1) * 16);
            o1[e >> 1] |= s1_ << ((e & 1) * 16);
            o2[e >> 1] |= s2_ << ((e & 1) * 16);
        }
        *(uint4*)(base + ((0 * 8 + kss) << 6)) = make_uint4(o0[0], o0[1], o0[2], o0[3]);
        *(uint4*)(base + ((1 * 8 + kss) << 6)) = make_uint4(o1[0], o1[1], o1[2], o1[3]);
        *(uint4*)(base + ((2 * 8 + kss) << 6)) = make_uint4(o2[0], o2[1], o2[2], o2[3]);
    }
    __syncthreads();
    WRITEC(&sBb[0][0]);
    __syncthreads();

    f32x4 acc2[4];
#pragma unroll
    for (int j = 0; j < 4; ++j) acc2[j] = (f32x4){0.f, 0.f, 0.f, 0.f};

    cur = 0;
#pragma unroll 1
    for (int c = 0; c < 12; ++c) {
        if (c < 11) LOADC(uhcpk + (c + 1) * 2048);
        const int p = c >> 1, hh = c & 1;
        const int spA = (PA_PACK >> (p * 4)) & 3;
        const short8v* sBs = (const short8v*)&sBb[cur][0];
#pragma unroll
        for (int ks2 = 0; ks2 < 4; ++ks2) {
            int ks = hh * 4 + ks2;
            short8v a = *(const short8v*)(arbase + ((spA * 8 + (ks ^ mswz)) << 6));
#pragma unroll
            for (int jj = 0; jj < 4; ++jj)
                acc2[jj] = __builtin_amdgcn_mfma_f32_16x16x32_bf16(a, sBs[(ks2 * 8 + jh * 4 + jj) * 64 + lane], acc2[jj], 0, 0, 0);
        }
        if (c < 11) WRITEC(&sBb[cur ^ 1][0]);
        __syncthreads();
        cur ^= 1;
    }

#pragma unroll
    for (int jj = 0; jj < 4; ++jj)
#pragma unroll
        for (int r = 0; r < 4; ++r) {
            int col = (jh * 4 + jj) * 16 + li;
            size_t gn = (size_t)(s0 + rbase + r);
            float f = freg[jj][r];
            float whcv = whcw[gn * 128 + col];
            float c1 = h[(2 * gn + 1) * 128 + col];
            float c2 = h[(2 * gn + 2) * 128 + col];
            float t = tanhf(acc2[jj][r] + whcv);
            h[gn * 128 + col] = f * (c1 + c2) + (1.0f - f) * t;
        }
}

// =================== tail: levels 5..0 in one block (fp32, proven) ===================
__global__ __launch_bounds__(NT) void tail_kernel(
    const float* __restrict__ ws_all, float* __restrict__ h)
{
    __shared__ __align__(16) float bufA[64 * 128];
    __shared__ __align__(16) float bufB[32 * 128];
    __shared__ __align__(16) float sF[8 * 128];
    const float* uft  = ws_all + UFT_OFF;
    const float* uhct = ws_all + UHCT_OFF;
    const float* whcw = ws_all + WHC_OFF;
    const float* wfw  = ws_all + WF_OFF;

    const int tid = threadIdx.x;
    const int jq = tid & 31;  const int j0 = jq << 2;
    const int iq = tid >> 5;

    {
        const float4* hg = (const float4*)(h + (size_t)63 * 128);
        float4* b4 = (float4*)bufA;
        for (int idx = tid; idx < 64 * 32; idx += NT) b4[idx] = hg[idx];
    }
    __syncthreads();

    float* child = bufA;
    float* cur   = bufB;

    for (int lvl = 5; lvl >= 0; --lvl) {
        const int start = (1 << lvl) - 1;
        const int size  = 1 << lvl;
        for (int pass = 0; pass < size; pass += 8) {
            const int ni = pass + iq;
            const bool act = (ni < size);
            float f[4] = {0.f, 0.f, 0.f, 0.f};
            if (act) {
                const float* hc = child + ni * 256;
                float fv[4] = {0.f, 0.f, 0.f, 0.f};
                for (int k = 0; k < 256; k += 4) {
#pragma unroll
                    for (int u = 0; u < 4; ++u) {
                        float av = hc[k + u];
                        float4 w = *(const float4*)&uft[(size_t)(k + u) * 128 + j0];
                        fv[0] = fmaf(w.x, av, fv[0]);
                        fv[1] = fmaf(w.y, av, fv[1]);
                        fv[2] = fmaf(w.z, av, fv[2]);
                        fv[3] = fmaf(w.w, av, fv[3]);
                    }
                }
                const int gn = start + ni;
                float4 wfv = *(const float4*)&wfw[(size_t)gn * 128 + j0];
                const float* wfp = (const float*)&wfv;
#pragma unroll
                for (int j = 0; j < 4; ++j) {
                    f[j] = sigmoid_(fv[j] + wfp[j]);
                    sF[iq * 128 + j0 + j] = f[j];
                }
            }
            __syncthreads();
            if (act) {
                const float* hc = child + ni * 256;
                const float* fr = sF + iq * 128;
                float cv[4] = {0.f, 0.f, 0.f, 0.f};
                for (int k = 0; k < 256; k += 4) {
#pragma unroll
                    for (int u = 0; u < 4; ++u) {
                        float av = hc[k + u] * fr[(k + u) & 127];
                        float4 w = *(const float4*)&uhct[(size_t)(k + u) * 128 + j0];
                        cv[0] = fmaf(w.x, av, cv[0]);
                        cv[1] = fmaf(w.y, av, cv[1]);
                        cv[2] = fmaf(w.z, av, cv[2]);
                        cv[3] = fmaf(w.w, av, cv[3]);
                    }
                }
                const int gn = start + ni;
                float4 whcv = *(const float4*)&whcw[(size_t)gn * 128 + j0];
                const float* wp = (const float*)&whcv;
                float4 o;
                float* op = (float*)&o;
#pragma unroll
                for (int j = 0; j < 4; ++j) {
                    float hsum = hc[j0 + j] + hc[128 + j0 + j];
                    float t = tanhf(cv[j] + wp[j]);
                    op[j] = f[j] * hsum + (1.0f - f[j]) * t;
                }
                *(float4*)&cur[ni * 128 + j0] = o;
                *(float4*)&h[(size_t)gn * 128 + j0] = o;
            }
            __syncthreads();
        }
        float* t = child; child = cur; cur = t;
    }
}

// =================== fallback path (no workspace; proven) ===================

__global__ __launch_bounds__(NT) void fb_leaf(
    const float* __restrict__ x, const float* __restrict__ Ww,
    const float* __restrict__ Wb, float* __restrict__ h, int start, int size)
{
    __shared__ float sA[32 * 128];
    __shared__ float sW[16 * 260];
    const int tid = threadIdx.x;
    const int nbase = blockIdx.x * 32;
    const int s0 = start + nbase;
    const int nb = min(32, size - nbase);
    const int jq = tid & 31, iq = tid >> 5;
    const int j0 = jq << 2, i0 = iq << 2;
    {
        const float4* xg = (const float4*)(x + (size_t)s0 * 128);
        float4* sA4 = (float4*)sA;
        for (int idx = tid; idx < nb * 32; idx += NT) sA4[idx] = xg[idx];
    }
    float whc[4][4], wf[4][4];
#pragma unroll
    for (int j = 0; j < 4; ++j)
#pragma unroll
        for (int i = 0; i < 4; ++i) { whc[j][i] = 0.f; wf[j][i] = 0.f; }
    for (int k0 = 0; k0 < 128; k0 += 16) {
        __syncthreads();
        const float4* Wg = (const float4*)Ww;
        for (int idx = tid; idx < 256 * 4; idx += NT) {
            int j2 = idx >> 2, kq = idx & 3;
            float4 v = Wg[j2 * 32 + (k0 >> 2) + kq];
            int kb = kq << 2;
            sW[(kb + 0) * 260 + j2] = v.x; sW[(kb + 1) * 260 + j2] = v.y;
            sW[(kb + 2) * 260 + j2] = v.z; sW[(kb + 3) * 260 + j2] = v.w;
        }
        __syncthreads();
#pragma unroll
        for (int kk = 0; kk < 16; kk += 4) {
            float4 a4[4];
#pragma unroll
            for (int i = 0; i < 4; ++i)
                a4[i] = ((const float4*)sA)[(i0 + i) * 32 + ((k0 + kk) >> 2)];
#pragma unroll
            for (int u = 0; u < 4; ++u) {
                int k = kk + u;
                float4 w0 = *((const float4*)&sW[k * 260 + j0]);
                float4 w1 = *((const float4*)&sW[k * 260 + 128 + j0]);
                const float* w0p = (const float*)&w0;
                const float* w1p = (const float*)&w1;
#pragma unroll
                for (int i = 0; i < 4; ++i) {
                    float av = ((const float*)&a4[i])[u];
#pragma unroll
                    for (int j = 0; j < 4; ++j) {
                        whc[j][i] = fmaf(w0p[j], av, whc[j][i]);
                        wf[j][i]  = fmaf(w1p[j], av, wf[j][i]);
                    }
                }
            }
        }
    }
#pragma unroll
    for (int i = 0; i < 4; ++i) {
        if (i0 + i < nb) {
            float4 o; float* op = (float*)&o;
#pragma unroll
            for (int j = 0; j < 4; ++j) {
                float f = sigmoid_(wf[j][i] + Wb[128 + j0 + j]);
                op[j] = (1.0f - f) * tanhf(whc[j][i] + Wb[j0 + j]);
            }
            *(float4*)&h[((size_t)(s0 + i0 + i)) * 128 + j0] = o;
        }
    }
}

__global__ __launch_bounds__(NT) void fb_internal(
    const float* __restrict__ x, const float* __restrict__ Ww,
    const float* __restrict__ Wb, const float* __restrict__ Uf,
    const float* __restrict__ Uhc, float* __restrict__ h, int start, int size)
{
    __shared__ float sA[32 * 256];
    __shared__ float sW[4224];
    const int tid = threadIdx.x;
    const int nbase = blockIdx.x * 32;
    const int s0 = start + nbase;
    const int nb = min(32, size - nbase);
    const int jq = tid & 31, iq = tid >> 5;
    const int j0 = jq << 2, i0 = iq << 2;
    {
        const float4* xg = (const float4*)(x + (size_t)s0 * 128);
        float4* sA4 = (float4*)sA;
        for (int idx = tid; idx < nb * 32; idx += NT) sA4[idx] = xg[idx];
    }
    float whc[4][4], wf[4][4];
#pragma unroll
    for (int j = 0; j < 4; ++j)
#pragma unroll
        for (int i = 0; i < 4; ++i) { whc[j][i] = 0.f; wf[j][i] = 0.f; }
    for (int k0 = 0; k0 < 128; k0 += 16) {
        __syncthreads();
        const float4* Wg = (const float4*)Ww;
        for (int idx = tid; idx < 256 * 4; idx += NT) {
            int j2 = idx >> 2, kq = idx & 3;
            float4 v = Wg[j2 * 32 + (k0 >> 2) + kq];
            int kb = kq << 2;
            sW[(kb + 0) * 260 + j2] = v.x; sW[(kb + 1) * 260 + j2] = v.y;
            sW[(kb + 2) * 260 + j2] = v.z; sW[(kb + 3) * 260 + j2] = v.w;
        }
        __syncthreads();
#pragma unroll
        for (int kk = 0; kk < 16; kk += 4) {
            float4 a4[4];
#pragma unroll
            for (int i = 0; i < 4; ++i)
                a4[i] = ((const float4*)sA)[(i0 + i) * 32 + ((k0 + kk) >> 2)];
#pragma unroll
            for (int u = 0; u < 4; ++u) {
                int k = kk + u;
                float4 w0 = *((const float4*)&sW[k * 260 + j0]);
                float4 w1 = *((const float4*)&sW[k * 260 + 128 + j0]);
                const float* w0p = (const float*)&w0;
                const float* w1p = (const float*)&w1;
#pragma unroll
                for (int i = 0; i < 4; ++i) {
                    float av = ((const float*)&a4[i])[u];
#pragma unroll
                    for (int j = 0; j < 4; ++j) {
                        whc[j][i] = fmaf(w0p[j], av, whc[j][i]);
                        wf[j][i]  = fmaf(w1p[j], av, wf[j][i]);
                    }
                }
            }
        }
    }
#pragma unroll
    for (int j = 0; j < 4; ++j) {
        float bhc = Wb[j0 + j], bf = Wb[128 + j0 + j];
#pragma unroll
        for (int i = 0; i < 4; ++i) { whc[j][i] += bhc; wf[j][i] += bf; }
    }
    __syncthreads();
    {
        const float4* hg = (const float4*)(h + ((size_t)2 * s0 + 1) * 128);
        float4* sA4 = (float4*)sA;
        for (int idx = tid; idx < nb * 64; idx += NT) sA4[idx] = hg[idx];
    }
    float fv[4][4];
#pragma unroll
    for (int j = 0; j < 4; ++j)
#pragma unroll
        for (int i = 0; i < 4; ++i) fv[j][i] = 0.f;
    for (int k0 = 0; k0 < 256; k0 += 32) {
        __syncthreads();
        const float4* Ug = (const float4*)Uf;
        for (int idx = tid; idx < 128 * 8; idx += NT) {
            int j2 = idx >> 3, kq = idx & 7;
            float4 v = Ug[j2 * 64 + (k0 >> 2) + kq];
            int kb = kq << 2;
            sW[(kb + 0) * 132 + j2] = v.x; sW[(kb + 1) * 132 + j2] = v.y;
            sW[(kb + 2) * 132 + j2] = v.z; sW[(kb + 3) * 132 + j2] = v.w;
        }
        __syncthreads();
#pragma unroll
        for (int kk = 0; kk < 32; kk += 4) {
            float4 a4[4];
#pragma unroll
            for (int i = 0; i < 4; ++i)
                a4[i] = ((const float4*)sA)[(i0 + i) * 64 + ((k0 + kk) >> 2)];
#pragma unroll
            for (int u = 0; u < 4; ++u) {
                int k = kk + u;
                float4 w = *((const float4*)&sW[k * 132 + j0]);
                const float* wp = (const float*)&w;
#pragma unroll
                for (int i = 0; i < 4; ++i) {
                    float av = ((const float*)&a4[i])[u];
#pragma unroll
                    for (int j = 0; j < 4; ++j)
                        fv[j][i] = fmaf(wp[j], av, fv[j][i]);
                }
            }
        }
    }
#pragma unroll
    for (int j = 0; j < 4; ++j)
#pragma unroll
        for (int i = 0; i < 4; ++i)
            fv[j][i] = sigmoid_(fv[j][i] + wf[j][i]);
    __syncthreads();
    float hs[4][4];
#pragma unroll
    for (int i = 0; i < 4; ++i) {
        float4* row = (float4*)&sA[(i0 + i) * 256];
        float4 c0 = row[jq], c1 = row[32 + jq];
        hs[0][i] = c0.x + c1.x; hs[1][i] = c0.y + c1.y;
        hs[2][i] = c0.z + c1.z; hs[3][i] = c0.w + c1.w;
        c0.x *= fv[0][i]; c0.y *= fv[1][i]; c0.z *= fv[2][i]; c0.w *= fv[3][i];
        c1.x *= fv[0][i]; c1.y *= fv[1][i]; c1.z *= fv[2][i]; c1.w *= fv[3][i];
        row[jq] = c0; row[32 + jq] = c1;
    }
    float cv[4][4];
#pragma unroll
    for (int j = 0; j < 4; ++j)
#pragma unroll
        for (int i = 0; i < 4; ++i) cv[j][i] = 0.f;
    for (int k0 = 0; k0 < 256; k0 += 32) {
        __syncthreads();
        const float4* Ug = (const float4*)Uhc;
        for (int idx = tid; idx < 128 * 8; idx += NT) {
            int j2 = idx >> 3, kq = idx & 7;
            float4 v = Ug[j2 * 64 + (k0 >> 2) + kq];
            int kb = kq << 2;
            sW[(kb + 0) * 132 + j2] = v.x; sW[(kb + 1) * 132 + j2] = v.y;
            sW[(kb + 2) * 132 + j2] = v.z; sW[(kb + 3) * 132 + j2] = v.w;
        }
        __syncthreads();
#pragma unroll
        for (int kk = 0; kk < 32; kk += 4) {
            float4 a4[4];
#pragma unroll
            for (int i = 0; i < 4; ++i)
                a4[i] = ((const float4*)sA)[(i0 + i) * 64 + ((k0 + kk) >> 2)];
#pragma unroll
            for (int u = 0; u < 4; ++u) {
                int k = kk + u;
                float4 w = *((const float4*)&sW[k * 132 + j0]);
                const float* wp = (const float*)&w;
#pragma unroll
                for (int i = 0; i < 4; ++i) {
                    float av = ((const float*)&a4[i])[u];
#pragma unroll
                    for (int j = 0; j < 4; ++j)
                        cv[j][i] = fmaf(wp[j], av, cv[j][i]);
                }
            }
        }
    }
#pragma unroll
    for (int i = 0; i < 4; ++i) {
        if (i0 + i < nb) {
            float4 o; float* op = (float*)&o;
#pragma unroll
            for (int j = 0; j < 4; ++j) {
                float t = tanhf(cv[j][i] + whc[j][i]);
                op[j] = fv[j][i] * hs[j][i] + (1.0f - fv[j][i]) * t;
            }
            *(float4*)&h[((size_t)(s0 + i0 + i)) * 128 + j0] = o;
        }
    }
}

// =================== launcher ===================

extern "C" void kernel_launch(void* const* d_in, const int* in_sizes, int n_in,
                              void* d_out, int out_size, void* d_ws, size_t ws_size,
                              hipStream_t stream)
{
    (void)in_sizes; (void)n_in; (void)out_size;
    const float* x   = (const float*)d_in[0];
    const float* Ww  = (const float*)d_in[1];
    const float* Wb  = (const float*)d_in[2];
    const float* Uf  = (const float*)d_in[3];
    const float* Uhc = (const float*)d_in[4];
    float* h = (float*)d_out;
    const int depth = 18;

    if (ws_size >= WS_BYTES) {
        float* ws = (float*)d_ws;
        prep_pack<<<544, NT, 0, stream>>>(Ww, Uf, Uhc, ws);
        wx_mfma5<<<2048, 512, 0, stream>>>(x, ws, Wb, ws, h);
        for (int lvl = 16; lvl >= 7; --lvl) {
            int start = (1 << lvl) - 1;
            int grid  = 1 << (lvl - 7);
            b1_128<<<grid, 512, 0, stream>>>(ws, ws, h, start);
            b2_128<<<grid, 512, 0, stream>>>(ws, h, start);
        }
        lvl_fused<<<1, 512, 0, stream>>>(ws, h, 63);   // level 6 (64 nodes)
        tail_kernel<<<1, NT, 0, stream>>>(ws, h);
    } else {
        {
            int lvl = depth - 1;
            int start = (1 << lvl) - 1, size = 1 << lvl;
            fb_leaf<<<(size + 31) / 32, NT, 0, stream>>>(x, Ww, Wb, h, start, size);
        }
        for (int lvl = depth - 2; lvl >= 0; --lvl) {
            int start = (1 << lvl) - 1, size = 1 << lvl;
            fb_internal<<<(size + 31) / 32, NT, 0, stream>>>(x, Ww, Wb, Uf, Uhc, h, start, size);
        }
    }
}

// Round 12
// 802.781 us; speedup vs baseline: 1.3660x; 1.3660x over previous
//
#include <hip/hip_runtime.h>
#include <cmath>

#define NT 256

// ---- problem constants (DEPTH=18, N_ARY=2, H=128, X=128) ----
#define NTOT   262143     // node count (ids 0..262142)
#define NINT   131071     // internal nodes: ids 0 .. 131070

// ws layout (floats) — identical to rounds 6..11 (proven available)
#define WHC_OFF   0                        // [NINT][128] (bias included)
#define WF_OFF    (NINT * 128)             // [NINT][128] (bias included; never overwritten)
#define UFT_OFF   (2 * NINT * 128)         // [256][128] f32
#define UHCT_OFF  (UFT_OFF + 32768)        // [256][128] f32
#define PKWW_OFF  (UHCT_OFF + 32768)       // 24576 slots x 16B bf16 frags
#define PKUF_OFF  (PKWW_OFF + 98304)       // 24576 slots x 16B
#define PKUHC_OFF (PKUF_OFF + 98304)       // 24576 slots x 16B
#define WS_FLOATS (PKUHC_OFF + 98304)
#define WS_BYTES  ((size_t)WS_FLOATS * 4)  // ~135.7 MB

// 6 product blocks p: A-term PA[p], B-term PB[p]
#define PA_PACK 0x120100   // {0,0,1,0,2,1}
#define PB_PACK 0x102010   // {0,1,0,2,0,1}

typedef __attribute__((ext_vector_type(8))) short short8v;
typedef __attribute__((ext_vector_type(4))) float f32x4;

__device__ __forceinline__ float sigmoid_(float v) {
    return 1.0f / (1.0f + expf(-v));
}

// truncation split of fp32 into 3 bf16 terms (exact residuals)
__device__ __forceinline__ void split3(float a, unsigned &t0, unsigned &t1, unsigned &t2) {
    unsigned u0 = __float_as_uint(a) & 0xffff0000u;
    float f0 = __uint_as_float(u0);
    float r1 = a - f0;
    unsigned u1 = __float_as_uint(r1) & 0xffff0000u;
    float f1 = __uint_as_float(u1);
    float r2 = r1 - f1;
    unsigned u2 = __float_as_uint(r2) & 0xffff0000u;
    t0 = u0 >> 16; t1 = u1 >> 16; t2 = u2 >> 16;
}
__device__ __forceinline__ float bf2f(unsigned hbits) {
    return __uint_as_float(hbits << 16);
}

// =================== weight prep (round-6, proven) ===================
__global__ __launch_bounds__(NT) void prep_pack(
    const float* __restrict__ Ww, const float* __restrict__ Uf,
    const float* __restrict__ Uhc, float* __restrict__ ws)
{
    int t = blockIdx.x * NT + threadIdx.x;
    if (t < 32768) { int k = t >> 7, j = t & 127; ws[UFT_OFF + t] = Uf[j * 256 + k]; return; }
    t -= 32768;
    if (t < 32768) { int k = t >> 7, j = t & 127; ws[UHCT_OFF + t] = Uhc[j * 256 + k]; return; }
    t -= 32768;

    const float* src; int term; uint4* dst; int q;
    if (t < 24576) {                       // PKWW
        q = t;
        int l = q & 63, j = (q >> 6) & 15, s = q >> 10;
        int p = s >> 2, ks = s & 3;
        term = (PB_PACK >> (p * 4)) & 3;
        int kb = ks * 32 + (l >> 4) * 8, col = j * 16 + (l & 15);
        src = Ww + col * 128 + kb;
        dst = (uint4*)(ws + PKWW_OFF);
    } else if (t < 49152) {                // PKUF
        q = t - 24576;
        int l = q & 63, j = (q >> 6) & 7, s = q >> 9;
        int p = s >> 3, ks = s & 7;
        term = (PB_PACK >> (p * 4)) & 3;
        int kb = ks * 32 + (l >> 4) * 8, col = j * 16 + (l & 15);
        src = Uf + col * 256 + kb;
        dst = (uint4*)(ws + PKUF_OFF);
    } else if (t < 73728) {                // PKUHC
        q = t - 49152;
        int l = q & 63, j = (q >> 6) & 7, s = q >> 9;
        int p = s >> 3, ks = s & 7;
        term = (PB_PACK >> (p * 4)) & 3;
        int kb = ks * 32 + (l >> 4) * 8, col = j * 16 + (l & 15);
        src = Uhc + col * 256 + kb;
        dst = (uint4*)(ws + PKUHC_OFF);
    } else return;

    unsigned hv[8];
#pragma unroll
    for (int e = 0; e < 8; ++e) {
        unsigned a, b, c; split3(src[e], a, b, c);
        hv[e] = (term == 0) ? a : (term == 1 ? b : c);
    }
    uint4 o;
    o.x = hv[0] | (hv[1] << 16); o.y = hv[2] | (hv[3] << 16);
    o.z = hv[4] | (hv[5] << 16); o.w = hv[6] | (hv[7] << 16);
    dst[q] = o;
}

// stage helpers: 2048 uint4 (32 KB) per chunk, 512 threads, 4 per thread
#define LOADC(srcbase) { const uint4* s_ = (srcbase); \
    nx0 = s_[tid]; nx1 = s_[tid + 512]; nx2 = s_[tid + 1024]; nx3 = s_[tid + 1536]; }
#define WRITEC(dstbase) { uint4* d_ = (dstbase); \
    d_[tid] = nx0; d_[tid + 512] = nx1; d_[tid + 1024] = nx2; d_[tid + 1536] = nx3; }

// =================== wx: 128 nodes/block, 8 waves, dbuf B chunks (r10, proven) ===================
__global__ __launch_bounds__(512) void wx_mfma4(
    const float* __restrict__ x, const float* __restrict__ ws_all,
    const float* __restrict__ Wb, float* __restrict__ ws, float* __restrict__ h)
{
    __shared__ short As[128 * 384];           // 96 KB A-pack
    __shared__ uint4 sBb[2][2048];            // 2 x 32 KB B chunk buffers
    char* Asb = (char*)As;
    const int tid = threadIdx.x;
    const int nbase = blockIdx.x * 128;
    const uint4* pkb = (const uint4*)(ws_all + PKWW_OFF);

    uint4 nx0, nx1, nx2, nx3;
    LOADC(pkb);                               // chunk 0 -> regs (lands during conversion)

    // ---- convert x tile -> 3-term bf16 A-pack ----
    for (int i = 0; i < 8; ++i) {
        int idx = i * 512 + tid;
        int m = idx >> 5, g = idx & 31;
        int node = nbase + m; if (node > NTOT - 1) node = NTOT - 1;
        float4 v = *(const float4*)(x + (size_t)node * 128 + g * 4);
        unsigned a0[4], a1[4], a2[4];
        split3(v.x, a0[0], a1[0], a2[0]); split3(v.y, a0[1], a1[1], a2[1]);
        split3(v.z, a0[2], a1[2], a2[2]); split3(v.w, a0[3], a1[3], a2[3]);
        int ks = g >> 3, kg = (g >> 1) & 3, hw = (g & 1) * 8;
        int kss = ks ^ ((m >> 2) & 3), kgs = kg ^ (m & 3);
        char* base = Asb + m * 768 + kgs * 16 + hw;
        *(uint2*)(base + ((0 * 4 + kss) << 6)) = make_uint2(a0[0] | (a0[1] << 16), a0[2] | (a0[3] << 16));
        *(uint2*)(base + ((1 * 4 + kss) << 6)) = make_uint2(a1[0] | (a1[1] << 16), a1[2] | (a1[3] << 16));
        *(uint2*)(base + ((2 * 4 + kss) << 6)) = make_uint2(a2[0] | (a2[1] << 16), a2[2] | (a2[3] << 16));
    }
    WRITEC(&sBb[0][0]);
    __syncthreads();

    const int lane = tid & 63, wv = tid >> 6;
    const int li = lane & 15, kg = lane >> 4;
    const int mf = wv * 16 + li;
    const int mswz = (mf >> 2) & 3;
    const char* arbase = Asb + mf * 768 + ((kg ^ (mf & 3)) << 4);

    f32x4 acc[16];
#pragma unroll
    for (int j = 0; j < 16; ++j) acc[j] = (f32x4){0.f, 0.f, 0.f, 0.f};

    int cur = 0;
#pragma unroll 1
    for (int c = 0; c < 12; ++c) {
        if (c < 11) LOADC(pkb + (c + 1) * 2048);
        const int p = c >> 1, hh = c & 1;
        const int spA = (PA_PACK >> (p * 4)) & 3;
        const short8v* sBs = (const short8v*)&sBb[cur][0];
#pragma unroll
        for (int ks2 = 0; ks2 < 2; ++ks2) {
            int ks = hh * 2 + ks2;
            short8v a = *(const short8v*)(arbase + ((spA * 4 + (ks ^ mswz)) << 6));
#pragma unroll
            for (int j = 0; j < 16; ++j)
                acc[j] = __builtin_amdgcn_mfma_f32_16x16x32_bf16(a, sBs[(ks2 * 16 + j) * 64 + lane], acc[j], 0, 0, 0);
        }
        if (c < 11) WRITEC(&sBb[cur ^ 1][0]);
        __syncthreads();
        cur ^= 1;
    }

    // ---- epilogue ----
    float* whcw = ws + WHC_OFF;
    float* wfw  = ws + WF_OFF;
    const int rbase = wv * 16 + kg * 4;
#pragma unroll
    for (int r = 0; r < 4; ++r) {
        int node = nbase + rbase + r;
        if (node >= NTOT) continue;
        if (node < NINT) {
#pragma unroll
            for (int j = 0; j < 16; ++j) {
                int col = j * 16 + li;
                float v = acc[j][r] + Wb[col];
                if (col < 128) whcw[(size_t)node * 128 + col] = v;
                else           wfw [(size_t)node * 128 + col - 128] = v;
            }
        } else {
#pragma unroll
            for (int j = 0; j < 8; ++j) {
                int col = j * 16 + li;
                float hc = acc[j][r] + Wb[col];
                float wf = acc[j + 8][r] + Wb[col + 128];
                float f = sigmoid_(wf);
                h[(size_t)node * 128 + col] = (1.0f - f) * tanhf(hc);
            }
        }
    }
}

// =================== fused level: P2 + in-LDS rescale + P3 + epilogue (r10, proven) ===================
// 64 nodes/block, 8 waves. Used for BIG levels (16..12).
__global__ __launch_bounds__(512) void lvl_fused(
    const float* __restrict__ ws_all, float* __restrict__ h, int start)
{
    __shared__ short As[64 * 768];            // 96 KB
    __shared__ uint4 sBb[2][2048];            // 2 x 32 KB
    char* Asb = (char*)As;
    float* f_lds = (float*)&sBb[0][0];        // reused as f[64][128] between P2 and P3
    const int tid = threadIdx.x;
    const int s0 = start + blockIdx.x * 64;
    const float* hbase = h + ((size_t)2 * s0 + 1) * 128;
    const uint4* ufpk  = (const uint4*)(ws_all + PKUF_OFF);
    const uint4* uhcpk = (const uint4*)(ws_all + PKUHC_OFF);
    const float* wfw   = ws_all + WF_OFF;
    const float* whcw  = ws_all + WHC_OFF;

    uint4 nx0, nx1, nx2, nx3;
    LOADC(ufpk);                              // Uf chunk 0 (lands during conversion)

    // ---- convert Hcat -> 3-term bf16 A-pack ----
    for (int i = 0; i < 8; ++i) {
        int idx = i * 512 + tid;
        int m = idx >> 6, g = idx & 63;
        float4 v = *(const float4*)(hbase + m * 256 + g * 4);
        unsigned a0[4], a1[4], a2[4];
        split3(v.x, a0[0], a1[0], a2[0]); split3(v.y, a0[1], a1[1], a2[1]);
        split3(v.z, a0[2], a1[2], a2[2]); split3(v.w, a0[3], a1[3], a2[3]);
        int ks = g >> 3, kg = (g >> 1) & 3, hw = (g & 1) * 8;
        int kss = ks ^ ((m >> 2) & 7), kgs = kg ^ (m & 3);
        char* base = Asb + m * 1536 + kgs * 16 + hw;
        *(uint2*)(base + ((0 * 8 + kss) << 6)) = make_uint2(a0[0] | (a0[1] << 16), a0[2] | (a0[3] << 16));
        *(uint2*)(base + ((1 * 8 + kss) << 6)) = make_uint2(a1[0] | (a1[1] << 16), a1[2] | (a1[3] << 16));
        *(uint2*)(base + ((2 * 8 + kss) << 6)) = make_uint2(a2[0] | (a2[1] << 16), a2[2] | (a2[3] << 16));
    }
    WRITEC(&sBb[0][0]);
    __syncthreads();

    const int lane = tid & 63, wv = tid >> 6;
    const int li = lane & 15, kg = lane >> 4;
    const int rt = wv & 3, jh = wv >> 2;
    const int mf = rt * 16 + li;
    const int mswz = (mf >> 2) & 7;
    const char* arbase = Asb + mf * 1536 + ((kg ^ (mf & 3)) << 4);
    const int rbase = rt * 16 + kg * 4;

    // ---- P2: f = sigmoid(hcat@UfT + wf) ----
    f32x4 acc[4];
#pragma unroll
    for (int j = 0; j < 4; ++j) acc[j] = (f32x4){0.f, 0.f, 0.f, 0.f};

    int cur = 0;
#pragma unroll 1
    for (int c = 0; c < 12; ++c) {
        if (c < 11) LOADC(ufpk + (c + 1) * 2048);
        const int p = c >> 1, hh = c & 1;
        const int spA = (PA_PACK >> (p * 4)) & 3;
        const short8v* sBs = (const short8v*)&sBb[cur][0];
#pragma unroll
        for (int ks2 = 0; ks2 < 4; ++ks2) {
            int ks = hh * 4 + ks2;
            short8v a = *(const short8v*)(arbase + ((spA * 8 + (ks ^ mswz)) << 6));
#pragma unroll
            for (int jj = 0; jj < 4; ++jj)
                acc[jj] = __builtin_amdgcn_mfma_f32_16x16x32_bf16(a, sBs[(ks2 * 8 + jh * 4 + jj) * 64 + lane], acc[jj], 0, 0, 0);
        }
        if (c < 11) WRITEC(&sBb[cur ^ 1][0]);
        __syncthreads();
        cur ^= 1;
    }
    float freg[4][4];
#pragma unroll
    for (int jj = 0; jj < 4; ++jj)
#pragma unroll
        for (int r = 0; r < 4; ++r) {
            int col = (jh * 4 + jj) * 16 + li;
            size_t gn = (size_t)(s0 + rbase + r);
            float f = sigmoid_(acc[jj][r] + wfw[gn * 128 + col]);
            freg[jj][r] = f;
            f_lds[(rbase + r) * 128 + col] = f;
        }
    __syncthreads();   // f_lds visible; all P2 reads of As done

    // ---- rescale A in place: A'' = split3(f[m][k&127] * hcat[m][k]) ----
    LOADC(uhcpk);      // Uhc chunk 0 (lands during rescale)
    for (int i = 0; i < 4; ++i) {
        int idx = i * 512 + tid;
        int kgr = idx & 3, ksr = (idx >> 2) & 7, m = idx >> 5;
        int kss = ksr ^ ((m >> 2) & 7);
        int kgs = kgr ^ (m & 3);
        char* base = Asb + m * 1536 + (kgs << 4);
        uint4 g0 = *(uint4*)(base + ((0 * 8 + kss) << 6));
        uint4 g1 = *(uint4*)(base + ((1 * 8 + kss) << 6));
        uint4 g2 = *(uint4*)(base + ((2 * 8 + kss) << 6));
        unsigned w0[4] = {g0.x, g0.y, g0.z, g0.w};
        unsigned w1[4] = {g1.x, g1.y, g1.z, g1.w};
        unsigned w2[4] = {g2.x, g2.y, g2.z, g2.w};
        unsigned o0[4] = {0, 0, 0, 0}, o1[4] = {0, 0, 0, 0}, o2[4] = {0, 0, 0, 0};
#pragma unroll
        for (int e = 0; e < 8; ++e) {
            unsigned h0 = (e & 1) ? (w0[e >> 1] >> 16) : (w0[e >> 1] & 0xffffu);
            unsigned h1 = (e & 1) ? (w1[e >> 1] >> 16) : (w1[e >> 1] & 0xffffu);
            unsigned h2 = (e & 1) ? (w2[e >> 1] >> 16) : (w2[e >> 1] & 0xffffu);
            float a = bf2f(h0) + bf2f(h1) + bf2f(h2);
            int kph = ksr * 32 + kgr * 8 + e;
            float pv = a * f_lds[m * 128 + (kph & 127)];
            unsigned s0_, s1_, s2_; split3(pv, s0_, s1_, s2_);
            o0[e >> 1] |= s0_ << ((e & 1) * 16);
            o1[e >> 1] |= s1_ << ((e & 1) * 16);
            o2[e >> 1] |= s2_ << ((e & 1) * 16);
        }
        *(uint4*)(base + ((0 * 8 + kss) << 6)) = make_uint4(o0[0], o0[1], o0[2], o0[3]);
        *(uint4*)(base + ((1 * 8 + kss) << 6)) = make_uint4(o1[0], o1[1], o1[2], o1[3]);
        *(uint4*)(base + ((2 * 8 + kss) << 6)) = make_uint4(o2[0], o2[1], o2[2], o2[3]);
    }
    __syncthreads();   // rescale done; f_lds reads done (sBb[0] reusable)
    WRITEC(&sBb[0][0]);
    __syncthreads();

    // ---- P3: cand = (f_rep*hcat)@UhcT ----
    f32x4 acc2[4];
#pragma unroll
    for (int j = 0; j < 4; ++j) acc2[j] = (f32x4){0.f, 0.f, 0.f, 0.f};

    cur = 0;
#pragma unroll 1
    for (int c = 0; c < 12; ++c) {
        if (c < 11) LOADC(uhcpk + (c + 1) * 2048);
        const int p = c >> 1, hh = c & 1;
        const int spA = (PA_PACK >> (p * 4)) & 3;
        const short8v* sBs = (const short8v*)&sBb[cur][0];
#pragma unroll
        for (int ks2 = 0; ks2 < 4; ++ks2) {
            int ks = hh * 4 + ks2;
            short8v a = *(const short8v*)(arbase + ((spA * 8 + (ks ^ mswz)) << 6));
#pragma unroll
            for (int jj = 0; jj < 4; ++jj)
                acc2[jj] = __builtin_amdgcn_mfma_f32_16x16x32_bf16(a, sBs[(ks2 * 8 + jh * 4 + jj) * 64 + lane], acc2[jj], 0, 0, 0);
        }
        if (c < 11) WRITEC(&sBb[cur ^ 1][0]);
        __syncthreads();
        cur ^= 1;
    }

    // ---- epilogue: h = f*(c1+c2) + (1-f)*tanh(cand + whc) ----
#pragma unroll
    for (int jj = 0; jj < 4; ++jj)
#pragma unroll
        for (int r = 0; r < 4; ++r) {
            int col = (jh * 4 + jj) * 16 + li;
            size_t gn = (size_t)(s0 + rbase + r);
            float f = freg[jj][r];
            float whcv = whcw[gn * 128 + col];
            float c1 = h[(2 * gn + 1) * 128 + col];
            float c2 = h[(2 * gn + 2) * 128 + col];
            float t = tanhf(acc2[jj][r] + whcv);
            h[gn * 128 + col] = f * (c1 + c2) + (1.0f - f) * t;
        }
}

// =================== internal level fp32 (round-2, proven) — small levels 11..6 ===================
#define B_NB 32
__global__ __launch_bounds__(NT) void level_kernel(
    const float* __restrict__ ws_all, float* __restrict__ h,
    int start, int size)
{
    __shared__ float sH[B_NB * 256];
    const float* uft  = ws_all + UFT_OFF;
    const float* uhct = ws_all + UHCT_OFF;
    const float* whcw = ws_all + WHC_OFF;
    const float* wfw  = ws_all + WF_OFF;

    const int tid = threadIdx.x;
    const int nbase = blockIdx.x * B_NB;
    const int s0 = start + nbase;
    const int nb = min(B_NB, size - nbase);

    const int jq = tid & 31;  const int j0 = jq << 2;
    const int iq = tid >> 5;  const int i0 = iq << 2;

    {
        const float4* hg = (const float4*)(h + ((size_t)2 * s0 + 1) * 128);
        float4* sH4 = (float4*)sH;
        for (int idx = tid; idx < nb * 64; idx += NT) sH4[idx] = hg[idx];
    }
    __syncthreads();

    const float4* sH4 = (const float4*)sH;

    float fv[4][4];
#pragma unroll
    for (int j = 0; j < 4; ++j)
#pragma unroll
        for (int i = 0; i < 4; ++i) fv[j][i] = 0.f;

    for (int k0 = 0; k0 < 256; k0 += 8) {
        float4 w[8];
#pragma unroll
        for (int u = 0; u < 8; ++u)
            w[u] = *(const float4*)&uft[(size_t)(k0 + u) * 128 + j0];
        float4 a[4][2];
#pragma unroll
        for (int i = 0; i < 4; ++i) {
            a[i][0] = sH4[(i0 + i) * 64 + (k0 >> 2)];
            a[i][1] = sH4[(i0 + i) * 64 + (k0 >> 2) + 1];
        }
#pragma unroll
        for (int u = 0; u < 8; ++u) {
            const float* wp = (const float*)&w[u];
#pragma unroll
            for (int i = 0; i < 4; ++i) {
                float av = ((const float*)&a[i][u >> 2])[u & 3];
#pragma unroll
                for (int j = 0; j < 4; ++j)
                    fv[j][i] = fmaf(wp[j], av, fv[j][i]);
            }
        }
    }
#pragma unroll
    for (int i = 0; i < 4; ++i) {
        float4 wfv = *(const float4*)&wfw[(size_t)(s0 + i0 + i) * 128 + j0];
        const float* wfp = (const float*)&wfv;
#pragma unroll
        for (int j = 0; j < 4; ++j)
            fv[j][i] = sigmoid_(fv[j][i] + wfp[j]);
    }

    __syncthreads();

    float hs[4][4];
#pragma unroll
    for (int i = 0; i < 4; ++i) {
        float4* row = (float4*)&sH[(i0 + i) * 256];
        float4 c0 = row[jq];
        float4 c1 = row[32 + jq];
        hs[0][i] = c0.x + c1.x;
        hs[1][i] = c0.y + c1.y;
        hs[2][i] = c0.z + c1.z;
        hs[3][i] = c0.w + c1.w;
        c0.x *= fv[0][i]; c0.y *= fv[1][i]; c0.z *= fv[2][i]; c0.w *= fv[3][i];
        c1.x *= fv[0][i]; c1.y *= fv[1][i]; c1.z *= fv[2][i]; c1.w *= fv[3][i];
        row[jq] = c0;
        row[32 + jq] = c1;
    }
    __syncthreads();

    float cv[4][4];
#pragma unroll
    for (int j = 0; j < 4; ++j)
#pragma unroll
        for (int i = 0; i < 4; ++i) cv[j][i] = 0.f;

    for (int k0 = 0; k0 < 256; k0 += 8) {
        float4 w[8];
#pragma unroll
        for (int u = 0; u < 8; ++u)
            w[u] = *(const float4*)&uhct[(size_t)(k0 + u) * 128 + j0];
        float4 a[4][2];
#pragma unroll
        for (int i = 0; i < 4; ++i) {
            a[i][0] = sH4[(i0 + i) * 64 + (k0 >> 2)];
            a[i][1] = sH4[(i0 + i) * 64 + (k0 >> 2) + 1];
        }
#pragma unroll
        for (int u = 0; u < 8; ++u) {
            const float* wp = (const float*)&w[u];
#pragma unroll
            for (int i = 0; i < 4; ++i) {
                float av = ((const float*)&a[i][u >> 2])[u & 3];
#pragma unroll
                for (int j = 0; j < 4; ++j)
                    cv[j][i] = fmaf(wp[j], av, cv[j][i]);
            }
        }
    }

#pragma unroll
    for (int i = 0; i < 4; ++i) {
        if (i0 + i < nb) {
            float4 whcv = *(const float4*)&whcw[(size_t)(s0 + i0 + i) * 128 + j0];
            const float* wp = (const float*)&whcv;
            float4 o;
            float* op = (float*)&o;
#pragma unroll
            for (int j = 0; j < 4; ++j) {
                float t = tanhf(cv[j][i] + wp[j]);
                op[j] = fv[j][i] * hs[j][i] + (1.0f - fv[j][i]) * t;
            }
            *(float4*)&h[(size_t)(s0 + i0 + i) * 128 + j0] = o;
        }
    }
}

// =================== tail: levels 5..0 in one block (fp32, proven) ===================
__global__ __launch_bounds__(NT) void tail_kernel(
    const float* __restrict__ ws_all, float* __restrict__ h)
{
    __shared__ __align__(16) float bufA[64 * 128];
    __shared__ __align__(16) float bufB[32 * 128];
    __shared__ __align__(16) float sF[8 * 128];
    const float* uft  = ws_all + UFT_OFF;
    const float* uhct = ws_all + UHCT_OFF;
    const float* whcw = ws_all + WHC_OFF;
    const float* wfw  = ws_all + WF_OFF;

    const int tid = threadIdx.x;
    const int jq = tid & 31;  const int j0 = jq << 2;
    const int iq = tid >> 5;

    {
        const float4* hg = (const float4*)(h + (size_t)63 * 128);
        float4* b4 = (float4*)bufA;
        for (int idx = tid; idx < 64 * 32; idx += NT) b4[idx] = hg[idx];
    }
    __syncthreads();

    float* child = bufA;
    float* cur   = bufB;

    for (int lvl = 5; lvl >= 0; --lvl) {
        const int start = (1 << lvl) - 1;
        const int size  = 1 << lvl;
        for (int pass = 0; pass < size; pass += 8) {
            const int ni = pass + iq;
            const bool act = (ni < size);
            float f[4] = {0.f, 0.f, 0.f, 0.f};
            if (act) {
                const float* hc = child + ni * 256;
                float fv[4] = {0.f, 0.f, 0.f, 0.f};
                for (int k = 0; k < 256; k += 4) {
#pragma unroll
                    for (int u = 0; u < 4; ++u) {
                        float av = hc[k + u];
                        float4 w = *(const float4*)&uft[(size_t)(k + u) * 128 + j0];
                        fv[0] = fmaf(w.x, av, fv[0]);
                        fv[1] = fmaf(w.y, av, fv[1]);
                        fv[2] = fmaf(w.z, av, fv[2]);
                        fv[3] = fmaf(w.w, av, fv[3]);
                    }
                }
                const int gn = start + ni;
                float4 wfv = *(const float4*)&wfw[(size_t)gn * 128 + j0];
                const float* wfp = (const float*)&wfv;
#pragma unroll
                for (int j = 0; j < 4; ++j) {
                    f[j] = sigmoid_(fv[j] + wfp[j]);
                    sF[iq * 128 + j0 + j] = f[j];
                }
            }
            __syncthreads();
            if (act) {
                const float* hc = child + ni * 256;
                const float* fr = sF + iq * 128;
                float cv[4] = {0.f, 0.f, 0.f, 0.f};
                for (int k = 0; k < 256; k += 4) {
#pragma unroll
                    for (int u = 0; u < 4; ++u) {
                        float av = hc[k + u] * fr[(k + u) & 127];
                        float4 w = *(const float4*)&uhct[(size_t)(k + u) * 128 + j0];
                        cv[0] = fmaf(w.x, av, cv[0]);
                        cv[1] = fmaf(w.y, av, cv[1]);
                        cv[2] = fmaf(w.z, av, cv[2]);
                        cv[3] = fmaf(w.w, av, cv[3]);
                    }
                }
                const int gn = start + ni;
                float4 whcv = *(const float4*)&whcw[(size_t)gn * 128 + j0];
                const float* wp = (const float*)&whcv;
                float4 o;
                float* op = (float*)&o;
#pragma unroll
                for (int j = 0; j < 4; ++j) {
                    float hsum = hc[j0 + j] + hc[128 + j0 + j];
                    float t = tanhf(cv[j] + wp[j]);
                    op[j] = f[j] * hsum + (1.0f - f[j]) * t;
                }
                *(float4*)&cur[ni * 128 + j0] = o;
                *(float4*)&h[(size_t)gn * 128 + j0] = o;
            }
            __syncthreads();
        }
        float* t = child; child = cur; cur = t;
    }
}

// =================== fallback path (no workspace; proven) ===================

__global__ __launch_bounds__(NT) void fb_leaf(
    const float* __restrict__ x, const float* __restrict__ Ww,
    const float* __restrict__ Wb, float* __restrict__ h, int start, int size)
{
    __shared__ float sA[32 * 128];
    __shared__ float sW[16 * 260];
    const int tid = threadIdx.x;
    const int nbase = blockIdx.x * 32;
    const int s0 = start + nbase;
    const int nb = min(32, size - nbase);
    const int jq = tid & 31, iq = tid >> 5;
    const int j0 = jq << 2, i0 = iq << 2;
    {
        const float4* xg = (const float4*)(x + (size_t)s0 * 128);
        float4* sA4 = (float4*)sA;
        for (int idx = tid; idx < nb * 32; idx += NT) sA4[idx] = xg[idx];
    }
    float whc[4][4], wf[4][4];
#pragma unroll
    for (int j = 0; j < 4; ++j)
#pragma unroll
        for (int i = 0; i < 4; ++i) { whc[j][i] = 0.f; wf[j][i] = 0.f; }
    for (int k0 = 0; k0 < 128; k0 += 16) {
        __syncthreads();
        const float4* Wg = (const float4*)Ww;
        for (int idx = tid; idx < 256 * 4; idx += NT) {
            int j2 = idx >> 2, kq = idx & 3;
            float4 v = Wg[j2 * 32 + (k0 >> 2) + kq];
            int kb = kq << 2;
            sW[(kb + 0) * 260 + j2] = v.x; sW[(kb + 1) * 260 + j2] = v.y;
            sW[(kb + 2) * 260 + j2] = v.z; sW[(kb + 3) * 260 + j2] = v.w;
        }
        __syncthreads();
#pragma unroll
        for (int kk = 0; kk < 16; kk += 4) {
            float4 a4[4];
#pragma unroll
            for (int i = 0; i < 4; ++i)
                a4[i] = ((const float4*)sA)[(i0 + i) * 32 + ((k0 + kk) >> 2)];
#pragma unroll
            for (int u = 0; u < 4; ++u) {
                int k = kk + u;
                float4 w0 = *((const float4*)&sW[k * 260 + j0]);
                float4 w1 = *((const float4*)&sW[k * 260 + 128 + j0]);
                const float* w0p = (const float*)&w0;
                const float* w1p = (const float*)&w1;
#pragma unroll
                for (int i = 0; i < 4; ++i) {
                    float av = ((const float*)&a4[i])[u];
#pragma unroll
                    for (int j = 0; j < 4; ++j) {
                        whc[j][i] = fmaf(w0p[j], av, whc[j][i]);
                        wf[j][i]  = fmaf(w1p[j], av, wf[j][i]);
                    }
                }
            }
        }
    }
#pragma unroll
    for (int i = 0; i < 4; ++i) {
        if (i0 + i < nb) {
            float4 o; float* op = (float*)&o;
#pragma unroll
            for (int j = 0; j < 4; ++j) {
                float f = sigmoid_(wf[j][i] + Wb[128 + j0 + j]);
                op[j] = (1.0f - f) * tanhf(whc[j][i] + Wb[j0 + j]);
            }
            *(float4*)&h[((size_t)(s0 + i0 + i)) * 128 + j0] = o;
        }
    }
}

__global__ __launch_bounds__(NT) void fb_internal(
    const float* __restrict__ x, const float* __restrict__ Ww,
    const float* __restrict__ Wb, const float* __restrict__ Uf,
    const float* __restrict__ Uhc, float* __restrict__ h, int start, int size)
{
    __shared__ float sA[32 * 256];
    __shared__ float sW[4224];
    const int tid = threadIdx.x;
    const int nbase = blockIdx.x * 32;
    const int s0 = start + nbase;
    const int nb = min(32, size - nbase);
    const int jq = tid & 31, iq = tid >> 5;
    const int j0 = jq << 2, i0 = iq << 2;
    {
        const float4* xg = (const float4*)(x + (size_t)s0 * 128);
        float4* sA4 = (float4*)sA;
        for (int idx = tid; idx < nb * 32; idx += NT) sA4[idx] = xg[idx];
    }
    float whc[4][4], wf[4][4];
#pragma unroll
    for (int j = 0; j < 4; ++j)
#pragma unroll
        for (int i = 0; i < 4; ++i) { whc[j][i] = 0.f; wf[j][i] = 0.f; }
    for (int k0 = 0; k0 < 128; k0 += 16) {
        __syncthreads();
        const float4* Wg = (const float4*)Ww;
        for (int idx = tid; idx < 256 * 4; idx += NT) {
            int j2 = idx >> 2, kq = idx & 3;
            float4 v = Wg[j2 * 32 + (k0 >> 2) + kq];
            int kb = kq << 2;
            sW[(kb + 0) * 260 + j2] = v.x; sW[(kb + 1) * 260 + j2] = v.y;
            sW[(kb + 2) * 260 + j2] = v.z; sW[(kb + 3) * 260 + j2] = v.w;
        }
        __syncthreads();
#pragma unroll
        for (int kk = 0; kk < 16; kk += 4) {
            float4 a4[4];
#pragma unroll
            for (int i = 0; i < 4; ++i)
                a4[i] = ((const float4*)sA)[(i0 + i) * 32 + ((k0 + kk) >> 2)];
#pragma unroll
            for (int u = 0; u < 4; ++u) {
                int k = kk + u;
                float4 w0 = *((const float4*)&sW[k * 260 + j0]);
                float4 w1 = *((const float4*)&sW[k * 260 + 128 + j0]);
                const float* w0p = (const float*)&w0;
                const float* w1p = (const float*)&w1;
#pragma unroll
                for (int i = 0; i < 4; ++i) {
                    float av = ((const float*)&a4[i])[u];
#pragma unroll
                    for (int j = 0; j < 4; ++j) {
                        whc[j][i] = fmaf(w0p[j], av, whc[j][i]);
                        wf[j][i]  = fmaf(w1p[j], av, wf[j][i]);
                    }
                }
            }
        }
    }
#pragma unroll
    for (int j = 0; j < 4; ++j) {
        float bhc = Wb[j0 + j], bf = Wb[128 + j0 + j];
#pragma unroll
        for (int i = 0; i < 4; ++i) { whc[j][i] += bhc; wf[j][i] += bf; }
    }
    __syncthreads();
    {
        const float4* hg = (const float4*)(h + ((size_t)2 * s0 + 1) * 128);
        float4* sA4 = (float4*)sA;
        for (int idx = tid; idx < nb * 64; idx += NT) sA4[idx] = hg[idx];
    }
    float fv[4][4];
#pragma unroll
    for (int j = 0; j < 4; ++j)
#pragma unroll
        for (int i = 0; i < 4; ++i) fv[j][i] = 0.f;
    for (int k0 = 0; k0 < 256; k0 += 32) {
        __syncthreads();
        const float4* Ug = (const float4*)Uf;
        for (int idx = tid; idx < 128 * 8; idx += NT) {
            int j2 = idx >> 3, kq = idx & 7;
            float4 v = Ug[j2 * 64 + (k0 >> 2) + kq];
            int kb = kq << 2;
            sW[(kb + 0) * 132 + j2] = v.x; sW[(kb + 1) * 132 + j2] = v.y;
            sW[(kb + 2) * 132 + j2] = v.z; sW[(kb + 3) * 132 + j2] = v.w;
        }
        __syncthreads();
#pragma unroll
        for (int kk = 0; kk < 32; kk += 4) {
            float4 a4[4];
#pragma unroll
            for (int i = 0; i < 4; ++i)
                a4[i] = ((const float4*)sA)[(i0 + i) * 64 + ((k0 + kk) >> 2)];
#pragma unroll
            for (int u = 0; u < 4; ++u) {
                int k = kk + u;
                float4 w = *((const float4*)&sW[k * 132 + j0]);
                const float* wp = (const float*)&w;
#pragma unroll
                for (int i = 0; i < 4; ++i) {
                    float av = ((const float*)&a4[i])[u];
#pragma unroll
                    for (int j = 0; j < 4; ++j)
                        fv[j][i] = fmaf(wp[j], av, fv[j][i]);
                }
            }
        }
    }
#pragma unroll
    for (int j = 0; j < 4; ++j)
#pragma unroll
        for (int i = 0; i < 4; ++i)
            fv[j][i] = sigmoid_(fv[j][i] + wf[j][i]);
    __syncthreads();
    float hs[4][4];
#pragma unroll
    for (int i = 0; i < 4; ++i) {
        float4* row = (float4*)&sA[(i0 + i) * 256];
        float4 c0 = row[jq], c1 = row[32 + jq];
        hs[0][i] = c0.x + c1.x; hs[1][i] = c0.y + c1.y;
        hs[2][i] = c0.z + c1.z; hs[3][i] = c0.w + c1.w;
        c0.x *= fv[0][i]; c0.y *= fv[1][i]; c0.z *= fv[2][i]; c0.w *= fv[3][i];
        c1.x *= fv[0][i]; c1.y *= fv[1][i]; c1.z *= fv[2][i]; c1.w *= fv[3][i];
        row[jq] = c0; row[32 + jq] = c1;
    }
    float cv[4][4];
#pragma unroll
    for (int j = 0; j < 4; ++j)
#pragma unroll
        for (int i = 0; i < 4; ++i) cv[j][i] = 0.f;
    for (int k0 = 0; k0 < 256; k0 += 32) {
        __syncthreads();
        const float4* Ug = (const float4*)Uhc;
        for (int idx = tid; idx < 128 * 8; idx += NT) {
            int j2 = idx >> 3, kq = idx & 7;
            float4 v = Ug[j2 * 64 + (k0 >> 2) + kq];
            int kb = kq << 2;
            sW[(kb + 0) * 132 + j2] = v.x; sW[(kb + 1) * 132 + j2] = v.y;
            sW[(kb + 2) * 132 + j2] = v.z; sW[(kb + 3) * 132 + j2] = v.w;
        }
        __syncthreads();
#pragma unroll
        for (int kk = 0; kk < 32; kk += 4) {
            float4 a4[4];
#pragma unroll
            for (int i = 0; i < 4; ++i)
                a4[i] = ((const float4*)sA)[(i0 + i) * 64 + ((k0 + kk) >> 2)];
#pragma unroll
            for (int u = 0; u < 4; ++u) {
                int k = kk + u;
                float4 w = *((const float4*)&sW[k * 132 + j0]);
                const float* wp = (const float*)&w;
#pragma unroll
                for (int i = 0; i < 4; ++i) {
                    float av = ((const float*)&a4[i])[u];
#pragma unroll
                    for (int j = 0; j < 4; ++j)
                        cv[j][i] = fmaf(wp[j], av, cv[j][i]);
                }
            }
        }
    }
#pragma unroll
    for (int i = 0; i < 4; ++i) {
        if (i0 + i < nb) {
            float4 o; float* op = (float*)&o;
#pragma unroll
            for (int j = 0; j < 4; ++j) {
                float t = tanhf(cv[j][i] + whc[j][i]);
                op[j] = fv[j][i] * hs[j][i] + (1.0f - fv[j][i]) * t;
            }
            *(float4*)&h[((size_t)(s0 + i0 + i)) * 128 + j0] = o;
        }
    }
}

// =================== launcher ===================

extern "C" void kernel_launch(void* const* d_in, const int* in_sizes, int n_in,
                              void* d_out, int out_size, void* d_ws, size_t ws_size,
                              hipStream_t stream)
{
    (void)in_sizes; (void)n_in; (void)out_size;
    const float* x   = (const float*)d_in[0];
    const float* Ww  = (const float*)d_in[1];
    const float* Wb  = (const float*)d_in[2];
    const float* Uf  = (const float*)d_in[3];
    const float* Uhc = (const float*)d_in[4];
    float* h = (float*)d_out;
    const int depth = 18;

    if (ws_size >= WS_BYTES) {
        float* ws = (float*)d_ws;
        prep_pack<<<544, NT, 0, stream>>>(Ww, Uf, Uhc, ws);
        wx_mfma4<<<2048, 512, 0, stream>>>(x, ws, Wb, ws, h);
        for (int lvl = 16; lvl >= 12; --lvl)                     // big levels: MFMA fused
            lvl_fused<<<1 << (lvl - 6), 512, 0, stream>>>(ws, h, (1 << lvl) - 1);
        for (int lvl = 11; lvl >= 6; --lvl) {                    // small levels: fp32, low latency
            int start = (1 << lvl) - 1;
            int size  = 1 << lvl;
            level_kernel<<<(size + B_NB - 1) / B_NB, NT, 0, stream>>>(ws, h, start, size);
        }
        tail_kernel<<<1, NT, 0, stream>>>(ws, h);
    } else {
        {
            int lvl = depth - 1;
            int start = (1 << lvl) - 1, size = 1 << lvl;
            fb_leaf<<<(size + 31) / 32, NT, 0, stream>>>(x, Ww, Wb, h, start, size);
        }
        for (int lvl = depth - 2; lvl >= 0; --lvl) {
            int start = (1 << lvl) - 1, size = 1 << lvl;
            fb_internal<<<(size + 31) / 32, NT, 0, stream>>>(x, Ww, Wb, Uf, Uhc, h, start, size);
        }
    }
}

// Round 13
// 799.798 us; speedup vs baseline: 1.3710x; 1.0037x over previous
//
#include <hip/hip_runtime.h>
#include <cmath>

#define NT 256

// ---- problem constants (DEPTH=18, N_ARY=2, H=128, X=128) ----
#define NTOT   262143     // node count (ids 0..262142)
#define NINT   131071     // internal nodes: ids 0 .. 131070

// ws layout (floats) — identical to rounds 6..12 (proven available)
#define WHC_OFF   0                        // [NINT][128] (bias included)
#define WF_OFF    (NINT * 128)             // [NINT][128] (bias included; never overwritten)
#define UFT_OFF   (2 * NINT * 128)         // [256][128] f32
#define UHCT_OFF  (UFT_OFF + 32768)        // [256][128] f32
#define PKWW_OFF  (UHCT_OFF + 32768)       // 24576 slots x 16B bf16 frags
#define PKUF_OFF  (PKWW_OFF + 98304)       // 24576 slots x 16B
#define PKUHC_OFF (PKUF_OFF + 98304)       // 24576 slots x 16B
#define WS_FLOATS (PKUHC_OFF + 98304)
#define WS_BYTES  ((size_t)WS_FLOATS * 4)  // ~135.7 MB

// 6 product blocks p: A-term PA[p], B-term PB[p]
#define PA_PACK 0x120100   // {0,0,1,0,2,1}
#define PB_PACK 0x102010   // {0,1,0,2,0,1}

typedef __attribute__((ext_vector_type(8))) short short8v;
typedef __attribute__((ext_vector_type(4))) float f32x4;

__device__ __forceinline__ float sigmoid_(float v) {
    return 1.0f / (1.0f + expf(-v));
}

// truncation split of fp32 into 3 bf16 terms (exact residuals)
__device__ __forceinline__ void split3(float a, unsigned &t0, unsigned &t1, unsigned &t2) {
    unsigned u0 = __float_as_uint(a) & 0xffff0000u;
    float f0 = __uint_as_float(u0);
    float r1 = a - f0;
    unsigned u1 = __float_as_uint(r1) & 0xffff0000u;
    float f1 = __uint_as_float(u1);
    float r2 = r1 - f1;
    unsigned u2 = __float_as_uint(r2) & 0xffff0000u;
    t0 = u0 >> 16; t1 = u1 >> 16; t2 = u2 >> 16;
}

// =================== weight prep (round-6, proven) ===================
__global__ __launch_bounds__(NT) void prep_pack(
    const float* __restrict__ Ww, const float* __restrict__ Uf,
    const float* __restrict__ Uhc, float* __restrict__ ws)
{
    int t = blockIdx.x * NT + threadIdx.x;
    if (t < 32768) { int k = t >> 7, j = t & 127; ws[UFT_OFF + t] = Uf[j * 256 + k]; return; }
    t -= 32768;
    if (t < 32768) { int k = t >> 7, j = t & 127; ws[UHCT_OFF + t] = Uhc[j * 256 + k]; return; }
    t -= 32768;

    const float* src; int term; uint4* dst; int q;
    if (t < 24576) {                       // PKWW
        q = t;
        int l = q & 63, j = (q >> 6) & 15, s = q >> 10;
        int p = s >> 2, ks = s & 3;
        term = (PB_PACK >> (p * 4)) & 3;
        int kb = ks * 32 + (l >> 4) * 8, col = j * 16 + (l & 15);
        src = Ww + col * 128 + kb;
        dst = (uint4*)(ws + PKWW_OFF);
    } else if (t < 49152) {                // PKUF
        q = t - 24576;
        int l = q & 63, j = (q >> 6) & 7, s = q >> 9;
        int p = s >> 3, ks = s & 7;
        term = (PB_PACK >> (p * 4)) & 3;
        int kb = ks * 32 + (l >> 4) * 8, col = j * 16 + (l & 15);
        src = Uf + col * 256 + kb;
        dst = (uint4*)(ws + PKUF_OFF);
    } else if (t < 73728) {                // PKUHC
        q = t - 49152;
        int l = q & 63, j = (q >> 6) & 7, s = q >> 9;
        int p = s >> 3, ks = s & 7;
        term = (PB_PACK >> (p * 4)) & 3;
        int kb = ks * 32 + (l >> 4) * 8, col = j * 16 + (l & 15);
        src = Uhc + col * 256 + kb;
        dst = (uint4*)(ws + PKUHC_OFF);
    } else return;

    unsigned hv[8];
#pragma unroll
    for (int e = 0; e < 8; ++e) {
        unsigned a, b, c; split3(src[e], a, b, c);
        hv[e] = (term == 0) ? a : (term == 1 ? b : c);
    }
    uint4 o;
    o.x = hv[0] | (hv[1] << 16); o.y = hv[2] | (hv[3] << 16);
    o.z = hv[4] | (hv[5] << 16); o.w = hv[6] | (hv[7] << 16);
    dst[q] = o;
}

// stage helpers: 2048 uint4 (32 KB) per chunk, 512 threads, 4 per thread
#define LOADC(srcbase) { const uint4* s_ = (srcbase); \
    nx0 = s_[tid]; nx1 = s_[tid + 512]; nx2 = s_[tid + 1024]; nx3 = s_[tid + 1536]; }
#define WRITEC(dstbase) { uint4* d_ = (dstbase); \
    d_[tid] = nx0; d_[tid + 512] = nx1; d_[tid + 1024] = nx2; d_[tid + 1536] = nx3; }

// =================== wx: 128 nodes/block, 8 waves, dbuf B chunks (r10, proven) ===================
__global__ __launch_bounds__(512) void wx_mfma4(
    const float* __restrict__ x, const float* __restrict__ ws_all,
    const float* __restrict__ Wb, float* __restrict__ ws, float* __restrict__ h)
{
    __shared__ short As[128 * 384];           // 96 KB A-pack
    __shared__ uint4 sBb[2][2048];            // 2 x 32 KB B chunk buffers
    char* Asb = (char*)As;
    const int tid = threadIdx.x;
    const int nbase = blockIdx.x * 128;
    const uint4* pkb = (const uint4*)(ws_all + PKWW_OFF);

    uint4 nx0, nx1, nx2, nx3;
    LOADC(pkb);                               // chunk 0 -> regs (lands during conversion)

    // ---- convert x tile -> 3-term bf16 A-pack ----
    for (int i = 0; i < 8; ++i) {
        int idx = i * 512 + tid;
        int m = idx >> 5, g = idx & 31;
        int node = nbase + m; if (node > NTOT - 1) node = NTOT - 1;
        float4 v = *(const float4*)(x + (size_t)node * 128 + g * 4);
        unsigned a0[4], a1[4], a2[4];
        split3(v.x, a0[0], a1[0], a2[0]); split3(v.y, a0[1], a1[1], a2[1]);
        split3(v.z, a0[2], a1[2], a2[2]); split3(v.w, a0[3], a1[3], a2[3]);
        int ks = g >> 3, kg = (g >> 1) & 3, hw = (g & 1) * 8;
        int kss = ks ^ ((m >> 2) & 3), kgs = kg ^ (m & 3);
        char* base = Asb + m * 768 + kgs * 16 + hw;
        *(uint2*)(base + ((0 * 4 + kss) << 6)) = make_uint2(a0[0] | (a0[1] << 16), a0[2] | (a0[3] << 16));
        *(uint2*)(base + ((1 * 4 + kss) << 6)) = make_uint2(a1[0] | (a1[1] << 16), a1[2] | (a1[3] << 16));
        *(uint2*)(base + ((2 * 4 + kss) << 6)) = make_uint2(a2[0] | (a2[1] << 16), a2[2] | (a2[3] << 16));
    }
    WRITEC(&sBb[0][0]);
    __syncthreads();

    const int lane = tid & 63, wv = tid >> 6;
    const int li = lane & 15, kg = lane >> 4;
    const int mf = wv * 16 + li;
    const int mswz = (mf >> 2) & 3;
    const char* arbase = Asb + mf * 768 + ((kg ^ (mf & 3)) << 4);

    f32x4 acc[16];
#pragma unroll
    for (int j = 0; j < 16; ++j) acc[j] = (f32x4){0.f, 0.f, 0.f, 0.f};

    int cur = 0;
#pragma unroll 1
    for (int c = 0; c < 12; ++c) {
        if (c < 11) LOADC(pkb + (c + 1) * 2048);
        const int p = c >> 1, hh = c & 1;
        const int spA = (PA_PACK >> (p * 4)) & 3;
        const short8v* sBs = (const short8v*)&sBb[cur][0];
#pragma unroll
        for (int ks2 = 0; ks2 < 2; ++ks2) {
            int ks = hh * 2 + ks2;
            short8v a = *(const short8v*)(arbase + ((spA * 4 + (ks ^ mswz)) << 6));
#pragma unroll
            for (int j = 0; j < 16; ++j)
                acc[j] = __builtin_amdgcn_mfma_f32_16x16x32_bf16(a, sBs[(ks2 * 16 + j) * 64 + lane], acc[j], 0, 0, 0);
        }
        if (c < 11) WRITEC(&sBb[cur ^ 1][0]);
        __syncthreads();
        cur ^= 1;
    }

    // ---- epilogue ----
    float* whcw = ws + WHC_OFF;
    float* wfw  = ws + WF_OFF;
    const int rbase = wv * 16 + kg * 4;
#pragma unroll
    for (int r = 0; r < 4; ++r) {
        int node = nbase + rbase + r;
        if (node >= NTOT) continue;
        if (node < NINT) {
#pragma unroll
            for (int j = 0; j < 16; ++j) {
                int col = j * 16 + li;
                float v = acc[j][r] + Wb[col];
                if (col < 128) whcw[(size_t)node * 128 + col] = v;
                else           wfw [(size_t)node * 128 + col - 128] = v;
            }
        } else {
#pragma unroll
            for (int j = 0; j < 8; ++j) {
                int col = j * 16 + li;
                float hc = acc[j][r] + Wb[col];
                float wf = acc[j + 8][r] + Wb[col + 128];
                float f = sigmoid_(wf);
                h[(size_t)node * 128 + col] = (1.0f - f) * tanhf(hc);
            }
        }
    }
}

// =================== lvl_reg: A-in-registers fused level (big levels 16..12) ===================
// 64 parents/block, 512 threads, 8 waves = (rt 0..3) x (jh 0..1); LDS 64 KB -> 2 blocks/CU.
// Lane (li,kg) owns A rows rt*16+li, k = ks*32+kg*8..+7 (8 consecutive floats, lane-local).

#define CHOFF(C) ((size_t)((((C) % 6) * 8 + ((C) / 6) * 4)) * 512)

#define CONVF(HLF, FS) { \
    _Pragma("unroll") \
    for (int ksl = 0; ksl < 4; ++ksl) { \
        const float* hp = h + (size_t)(2 * (s0 + rowp) + 1 + (HLF)) * 128 + kg * 8 + ksl * 32; \
        float4 va = *(const float4*)hp; \
        float4 vb = *(const float4*)(hp + 4); \
        if (FS) { \
            int fb = ksl * 32 + kg * 8; \
            float4 f0 = *(const float4*)&f_lds[rowp * 128 + (fb ^ fsw)]; \
            float4 f1 = *(const float4*)&f_lds[rowp * 128 + ((fb + 4) ^ fsw)]; \
            va.x *= f0.x; va.y *= f0.y; va.z *= f0.z; va.w *= f0.w; \
            vb.x *= f1.x; vb.y *= f1.y; vb.z *= f1.z; vb.w *= f1.w; \
        } \
        float ev[8] = {va.x, va.y, va.z, va.w, vb.x, vb.y, vb.z, vb.w}; \
        short8v t0, t1, t2; \
        _Pragma("unroll") \
        for (int e2 = 0; e2 < 8; ++e2) { \
            unsigned b0, b1, b2; split3(ev[e2], b0, b1, b2); \
            t0[e2] = (short)b0; t1[e2] = (short)b1; t2[e2] = (short)b2; \
        } \
        fr0[ksl] = t0; fr1[ksl] = t1; fr2[ksl] = t2; \
    } }

#define MFMAC(BUFP) { \
    const short8v* sBs = (const short8v*)(BUFP); \
    const int spA_ = (PA_PACK >> ((c % 6) * 4)) & 3; \
    _Pragma("unroll") \
    for (int ksl = 0; ksl < 4; ++ksl) { \
        short8v a = (spA_ == 0) ? fr0[ksl] : ((spA_ == 1) ? fr1[ksl] : fr2[ksl]); \
        _Pragma("unroll") \
        for (int jj = 0; jj < 4; ++jj) \
            acc[jj] = __builtin_amdgcn_mfma_f32_16x16x32_bf16(a, sBs[(ksl * 8 + jh * 4 + jj) * 64 + lane], acc[jj], 0, 0, 0); \
    } }

__global__ __launch_bounds__(512, 4) void lvl_reg(
    const float* __restrict__ ws_all, float* __restrict__ h, int start)
{
    __shared__ uint4 sBb[2][2048];            // 64 KB total
    float* f_lds = (float*)&sBb[0][0];        // f[64][128] (XOR-swizzled), lives through P3
    const int tid = threadIdx.x;
    const int s0 = start + blockIdx.x * 64;
    const uint4* ufpk  = (const uint4*)(ws_all + PKUF_OFF);
    const uint4* uhcpk = (const uint4*)(ws_all + PKUHC_OFF);
    const float* wfw   = ws_all + WF_OFF;
    const float* whcw  = ws_all + WHC_OFF;

    const int lane = tid & 63, wv = tid >> 6;
    const int li = lane & 15, kg = lane >> 4;
    const int rt = wv & 3, jh = wv >> 2;
    const int rowp = rt * 16 + li;            // A row (parent-local) this lane feeds
    const int fsw = (rowp & 7) << 2;          // f_lds bank swizzle
    const int rbase = rt * 16 + kg * 4;       // C rows this lane owns

    short8v fr0[4], fr1[4], fr2[4];
    f32x4 acc[4];
    uint4 nx0, nx1, nx2, nx3;

    // ================= P2: f = sigmoid(hcat@UfT + wf) =================
#pragma unroll
    for (int j = 0; j < 4; ++j) acc[j] = (f32x4){0.f, 0.f, 0.f, 0.f};
    CONVF(0, false);
    LOADC(ufpk + CHOFF(0));
    WRITEC(&sBb[0][0]);
    __syncthreads();
    int cur = 0;
#pragma unroll 1
    for (int c = 0; c < 12; ++c) {
        if (c < 11) LOADC(ufpk + CHOFF(c + 1));
        MFMAC(&sBb[cur][0]);
        if (c == 5) CONVF(1, false);
        if (c < 11) WRITEC(&sBb[cur ^ 1][0]);
        __syncthreads();
        cur ^= 1;
    }
    // f epilogue -> f_lds (buf0)
#pragma unroll
    for (int jj = 0; jj < 4; ++jj)
#pragma unroll
        for (int r = 0; r < 4; ++r) {
            int col = (jh * 4 + jj) * 16 + li;
            int rowl = rbase + r;
            size_t gn = (size_t)(s0 + rowl);
            float f = sigmoid_(acc[jj][r] + wfw[gn * 128 + col]);
            f_lds[rowl * 128 + (col ^ ((rowl & 7) << 2))] = f;
        }
    __syncthreads();

    // ================= P3: cand = (f_rep*hcat)@UhcT =================
#pragma unroll
    for (int j = 0; j < 4; ++j) acc[j] = (f32x4){0.f, 0.f, 0.f, 0.f};
    CONVF(0, true);
    LOADC(uhcpk + CHOFF(0));
#pragma unroll 1
    for (int c = 0; c < 12; ++c) {
        WRITEC(&sBb[1][0]);                   // buf1 only; f_lds (buf0) stays live
        if (c < 11) LOADC(uhcpk + CHOFF(c + 1));
        __syncthreads();
        MFMAC(&sBb[1][0]);
        if (c == 5) CONVF(1, true);
        __syncthreads();
    }

    // ---- final epilogue: h = f*(c1+c2) + (1-f)*tanh(cand + whc) ----
#pragma unroll
    for (int jj = 0; jj < 4; ++jj)
#pragma unroll
        for (int r = 0; r < 4; ++r) {
            int col = (jh * 4 + jj) * 16 + li;
            int rowl = rbase + r;
            size_t gn = (size_t)(s0 + rowl);
            float f = f_lds[rowl * 128 + (col ^ ((rowl & 7) << 2))];
            float whcv = whcw[gn * 128 + col];
            float c1 = h[(2 * gn + 1) * 128 + col];
            float c2 = h[(2 * gn + 2) * 128 + col];
            float t = tanhf(acc[jj][r] + whcv);
            h[gn * 128 + col] = f * (c1 + c2) + (1.0f - f) * t;
        }
}

// =================== internal level fp32 (round-2, proven) — small levels 11..6 ===================
#define B_NB 32
__global__ __launch_bounds__(NT) void level_kernel(
    const float* __restrict__ ws_all, float* __restrict__ h,
    int start, int size)
{
    __shared__ float sH[B_NB * 256];
    const float* uft  = ws_all + UFT_OFF;
    const float* uhct = ws_all + UHCT_OFF;
    const float* whcw = ws_all + WHC_OFF;
    const float* wfw  = ws_all + WF_OFF;

    const int tid = threadIdx.x;
    const int nbase = blockIdx.x * B_NB;
    const int s0 = start + nbase;
    const int nb = min(B_NB, size - nbase);

    const int jq = tid & 31;  const int j0 = jq << 2;
    const int iq = tid >> 5;  const int i0 = iq << 2;

    {
        const float4* hg = (const float4*)(h + ((size_t)2 * s0 + 1) * 128);
        float4* sH4 = (float4*)sH;
        for (int idx = tid; idx < nb * 64; idx += NT) sH4[idx] = hg[idx];
    }
    __syncthreads();

    const float4* sH4 = (const float4*)sH;

    float fv[4][4];
#pragma unroll
    for (int j = 0; j < 4; ++j)
#pragma unroll
        for (int i = 0; i < 4; ++i) fv[j][i] = 0.f;

    for (int k0 = 0; k0 < 256; k0 += 8) {
        float4 w[8];
#pragma unroll
        for (int u = 0; u < 8; ++u)
            w[u] = *(const float4*)&uft[(size_t)(k0 + u) * 128 + j0];
        float4 a[4][2];
#pragma unroll
        for (int i = 0; i < 4; ++i) {
            a[i][0] = sH4[(i0 + i) * 64 + (k0 >> 2)];
            a[i][1] = sH4[(i0 + i) * 64 + (k0 >> 2) + 1];
        }
#pragma unroll
        for (int u = 0; u < 8; ++u) {
            const float* wp = (const float*)&w[u];
#pragma unroll
            for (int i = 0; i < 4; ++i) {
                float av = ((const float*)&a[i][u >> 2])[u & 3];
#pragma unroll
                for (int j = 0; j < 4; ++j)
                    fv[j][i] = fmaf(wp[j], av, fv[j][i]);
            }
        }
    }
#pragma unroll
    for (int i = 0; i < 4; ++i) {
        float4 wfv = *(const float4*)&wfw[(size_t)(s0 + i0 + i) * 128 + j0];
        const float* wfp = (const float*)&wfv;
#pragma unroll
        for (int j = 0; j < 4; ++j)
            fv[j][i] = sigmoid_(fv[j][i] + wfp[j]);
    }

    __syncthreads();

    float hs[4][4];
#pragma unroll
    for (int i = 0; i < 4; ++i) {
        float4* row = (float4*)&sH[(i0 + i) * 256];
        float4 c0 = row[jq];
        float4 c1 = row[32 + jq];
        hs[0][i] = c0.x + c1.x;
        hs[1][i] = c0.y + c1.y;
        hs[2][i] = c0.z + c1.z;
        hs[3][i] = c0.w + c1.w;
        c0.x *= fv[0][i]; c0.y *= fv[1][i]; c0.z *= fv[2][i]; c0.w *= fv[3][i];
        c1.x *= fv[0][i]; c1.y *= fv[1][i]; c1.z *= fv[2][i]; c1.w *= fv[3][i];
        row[jq] = c0;
        row[32 + jq] = c1;
    }
    __syncthreads();

    float cv[4][4];
#pragma unroll
    for (int j = 0; j < 4; ++j)
#pragma unroll
        for (int i = 0; i < 4; ++i) cv[j][i] = 0.f;

    for (int k0 = 0; k0 < 256; k0 += 8) {
        float4 w[8];
#pragma unroll
        for (int u = 0; u < 8; ++u)
            w[u] = *(const float4*)&uhct[(size_t)(k0 + u) * 128 + j0];
        float4 a[4][2];
#pragma unroll
        for (int i = 0; i < 4; ++i) {
            a[i][0] = sH4[(i0 + i) * 64 + (k0 >> 2)];
            a[i][1] = sH4[(i0 + i) * 64 + (k0 >> 2) + 1];
        }
#pragma unroll
        for (int u = 0; u < 8; ++u) {
            const float* wp = (const float*)&w[u];
#pragma unroll
            for (int i = 0; i < 4; ++i) {
                float av = ((const float*)&a[i][u >> 2])[u & 3];
#pragma unroll
                for (int j = 0; j < 4; ++j)
                    cv[j][i] = fmaf(wp[j], av, cv[j][i]);
            }
        }
    }

#pragma unroll
    for (int i = 0; i < 4; ++i) {
        if (i0 + i < nb) {
            float4 whcv = *(const float4*)&whcw[(size_t)(s0 + i0 + i) * 128 + j0];
            const float* wp = (const float*)&whcv;
            float4 o;
            float* op = (float*)&o;
#pragma unroll
            for (int j = 0; j < 4; ++j) {
                float t = tanhf(cv[j][i] + wp[j]);
                op[j] = fv[j][i] * hs[j][i] + (1.0f - fv[j][i]) * t;
            }
            *(float4*)&h[(size_t)(s0 + i0 + i) * 128 + j0] = o;
        }
    }
}

// =================== tail: levels 5..0 in one block (fp32, proven) ===================
__global__ __launch_bounds__(NT) void tail_kernel(
    const float* __restrict__ ws_all, float* __restrict__ h)
{
    __shared__ __align__(16) float bufA[64 * 128];
    __shared__ __align__(16) float bufB[32 * 128];
    __shared__ __align__(16) float sF[8 * 128];
    const float* uft  = ws_all + UFT_OFF;
    const float* uhct = ws_all + UHCT_OFF;
    const float* whcw = ws_all + WHC_OFF;
    const float* wfw  = ws_all + WF_OFF;

    const int tid = threadIdx.x;
    const int jq = tid & 31;  const int j0 = jq << 2;
    const int iq = tid >> 5;

    {
        const float4* hg = (const float4*)(h + (size_t)63 * 128);
        float4* b4 = (float4*)bufA;
        for (int idx = tid; idx < 64 * 32; idx += NT) b4[idx] = hg[idx];
    }
    __syncthreads();

    float* child = bufA;
    float* cur   = bufB;

    for (int lvl = 5; lvl >= 0; --lvl) {
        const int start = (1 << lvl) - 1;
        const int size  = 1 << lvl;
        for (int pass = 0; pass < size; pass += 8) {
            const int ni = pass + iq;
            const bool act = (ni < size);
            float f[4] = {0.f, 0.f, 0.f, 0.f};
            if (act) {
                const float* hc = child + ni * 256;
                float fv[4] = {0.f, 0.f, 0.f, 0.f};
                for (int k = 0; k < 256; k += 4) {
#pragma unroll
                    for (int u = 0; u < 4; ++u) {
                        float av = hc[k + u];
                        float4 w = *(const float4*)&uft[(size_t)(k + u) * 128 + j0];
                        fv[0] = fmaf(w.x, av, fv[0]);
                        fv[1] = fmaf(w.y, av, fv[1]);
                        fv[2] = fmaf(w.z, av, fv[2]);
                        fv[3] = fmaf(w.w, av, fv[3]);
                    }
                }
                const int gn = start + ni;
                float4 wfv = *(const float4*)&wfw[(size_t)gn * 128 + j0];
                const float* wfp = (const float*)&wfv;
#pragma unroll
                for (int j = 0; j < 4; ++j) {
                    f[j] = sigmoid_(fv[j] + wfp[j]);
                    sF[iq * 128 + j0 + j] = f[j];
                }
            }
            __syncthreads();
            if (act) {
                const float* hc = child + ni * 256;
                const float* fr = sF + iq * 128;
                float cv[4] = {0.f, 0.f, 0.f, 0.f};
                for (int k = 0; k < 256; k += 4) {
#pragma unroll
                    for (int u = 0; u < 4; ++u) {
                        float av = hc[k + u] * fr[(k + u) & 127];
                        float4 w = *(const float4*)&uhct[(size_t)(k + u) * 128 + j0];
                        cv[0] = fmaf(w.x, av, cv[0]);
                        cv[1] = fmaf(w.y, av, cv[1]);
                        cv[2] = fmaf(w.z, av, cv[2]);
                        cv[3] = fmaf(w.w, av, cv[3]);
                    }
                }
                const int gn = start + ni;
                float4 whcv = *(const float4*)&whcw[(size_t)gn * 128 + j0];
                const float* wp = (const float*)&whcv;
                float4 o;
                float* op = (float*)&o;
#pragma unroll
                for (int j = 0; j < 4; ++j) {
                    float hsum = hc[j0 + j] + hc[128 + j0 + j];
                    float t = tanhf(cv[j] + wp[j]);
                    op[j] = f[j] * hsum + (1.0f - f[j]) * t;
                }
                *(float4*)&cur[ni * 128 + j0] = o;
                *(float4*)&h[(size_t)gn * 128 + j0] = o;
            }
            __syncthreads();
        }
        float* t = child; child = cur; cur = t;
    }
}

// =================== fallback path (no workspace; proven) ===================

__global__ __launch_bounds__(NT) void fb_leaf(
    const float* __restrict__ x, const float* __restrict__ Ww,
    const float* __restrict__ Wb, float* __restrict__ h, int start, int size)
{
    __shared__ float sA[32 * 128];
    __shared__ float sW[16 * 260];
    const int tid = threadIdx.x;
    const int nbase = blockIdx.x * 32;
    const int s0 = start + nbase;
    const int nb = min(32, size - nbase);
    const int jq = tid & 31, iq = tid >> 5;
    const int j0 = jq << 2, i0 = iq << 2;
    {
        const float4* xg = (const float4*)(x + (size_t)s0 * 128);
        float4* sA4 = (float4*)sA;
        for (int idx = tid; idx < nb * 32; idx += NT) sA4[idx] = xg[idx];
    }
    float whc[4][4], wf[4][4];
#pragma unroll
    for (int j = 0; j < 4; ++j)
#pragma unroll
        for (int i = 0; i < 4; ++i) { whc[j][i] = 0.f; wf[j][i] = 0.f; }
    for (int k0 = 0; k0 < 128; k0 += 16) {
        __syncthreads();
        const float4* Wg = (const float4*)Ww;
        for (int idx = tid; idx < 256 * 4; idx += NT) {
            int j2 = idx >> 2, kq = idx & 3;
            float4 v = Wg[j2 * 32 + (k0 >> 2) + kq];
            int kb = kq << 2;
            sW[(kb + 0) * 260 + j2] = v.x; sW[(kb + 1) * 260 + j2] = v.y;
            sW[(kb + 2) * 260 + j2] = v.z; sW[(kb + 3) * 260 + j2] = v.w;
        }
        __syncthreads();
#pragma unroll
        for (int kk = 0; kk < 16; kk += 4) {
            float4 a4[4];
#pragma unroll
            for (int i = 0; i < 4; ++i)
                a4[i] = ((const float4*)sA)[(i0 + i) * 32 + ((k0 + kk) >> 2)];
#pragma unroll
            for (int u = 0; u < 4; ++u) {
                int k = kk + u;
                float4 w0 = *((const float4*)&sW[k * 260 + j0]);
                float4 w1 = *((const float4*)&sW[k * 260 + 128 + j0]);
                const float* w0p = (const float*)&w0;
                const float* w1p = (const float*)&w1;
#pragma unroll
                for (int i = 0; i < 4; ++i) {
                    float av = ((const float*)&a4[i])[u];
#pragma unroll
                    for (int j = 0; j < 4; ++j) {
                        whc[j][i] = fmaf(w0p[j], av, whc[j][i]);
                        wf[j][i]  = fmaf(w1p[j], av, wf[j][i]);
                    }
                }
            }
        }
    }
#pragma unroll
    for (int i = 0; i < 4; ++i) {
        if (i0 + i < nb) {
            float4 o; float* op = (float*)&o;
#pragma unroll
            for (int j = 0; j < 4; ++j) {
                float f = sigmoid_(wf[j][i] + Wb[128 + j0 + j]);
                op[j] = (1.0f - f) * tanhf(whc[j][i] + Wb[j0 + j]);
            }
            *(float4*)&h[((size_t)(s0 + i0 + i)) * 128 + j0] = o;
        }
    }
}

__global__ __launch_bounds__(NT) void fb_internal(
    const float* __restrict__ x, const float* __restrict__ Ww,
    const float* __restrict__ Wb, const float* __restrict__ Uf,
    const float* __restrict__ Uhc, float* __restrict__ h, int start, int size)
{
    __shared__ float sA[32 * 256];
    __shared__ float sW[4224];
    const int tid = threadIdx.x;
    const int nbase = blockIdx.x * 32;
    const int s0 = start + nbase;
    const int nb = min(32, size - nbase);
    const int jq = tid & 31, iq = tid >> 5;
    const int j0 = jq << 2, i0 = iq << 2;
    {
        const float4* xg = (const float4*)(x + (size_t)s0 * 128);
        float4* sA4 = (float4*)sA;
        for (int idx = tid; idx < nb * 32; idx += NT) sA4[idx] = xg[idx];
    }
    float whc[4][4], wf[4][4];
#pragma unroll
    for (int j = 0; j < 4; ++j)
#pragma unroll
        for (int i = 0; i < 4; ++i) { whc[j][i] = 0.f; wf[j][i] = 0.f; }
    for (int k0 = 0; k0 < 128; k0 += 16) {
        __syncthreads();
        const float4* Wg = (const float4*)Ww;
        for (int idx = tid; idx < 256 * 4; idx += NT) {
            int j2 = idx >> 2, kq = idx & 3;
            float4 v = Wg[j2 * 32 + (k0 >> 2) + kq];
            int kb = kq << 2;
            sW[(kb + 0) * 260 + j2] = v.x; sW[(kb + 1) * 260 + j2] = v.y;
            sW[(kb + 2) * 260 + j2] = v.z; sW[(kb + 3) * 260 + j2] = v.w;
        }
        __syncthreads();
#pragma unroll
        for (int kk = 0; kk < 16; kk += 4) {
            float4 a4[4];
#pragma unroll
            for (int i = 0; i < 4; ++i)
                a4[i] = ((const float4*)sA)[(i0 + i) * 32 + ((k0 + kk) >> 2)];
#pragma unroll
            for (int u = 0; u < 4; ++u) {
                int k = kk + u;
                float4 w0 = *((const float4*)&sW[k * 260 + j0]);
                float4 w1 = *((const float4*)&sW[k * 260 + 128 + j0]);
                const float* w0p = (const float*)&w0;
                const float* w1p = (const float*)&w1;
#pragma unroll
                for (int i = 0; i < 4; ++i) {
                    float av = ((const float*)&a4[i])[u];
#pragma unroll
                    for (int j = 0; j < 4; ++j) {
                        whc[j][i] = fmaf(w0p[j], av, whc[j][i]);
                        wf[j][i]  = fmaf(w1p[j], av, wf[j][i]);
                    }
                }
            }
        }
    }
#pragma unroll
    for (int j = 0; j < 4; ++j) {
        float bhc = Wb[j0 + j], bf = Wb[128 + j0 + j];
#pragma unroll
        for (int i = 0; i < 4; ++i) { whc[j][i] += bhc; wf[j][i] += bf; }
    }
    __syncthreads();
    {
        const float4* hg = (const float4*)(h + ((size_t)2 * s0 + 1) * 128);
        float4* sA4 = (float4*)sA;
        for (int idx = tid; idx < nb * 64; idx += NT) sA4[idx] = hg[idx];
    }
    float fv[4][4];
#pragma unroll
    for (int j = 0; j < 4; ++j)
#pragma unroll
        for (int i = 0; i < 4; ++i) fv[j][i] = 0.f;
    for (int k0 = 0; k0 < 256; k0 += 32) {
        __syncthreads();
        const float4* Ug = (const float4*)Uf;
        for (int idx = tid; idx < 128 * 8; idx += NT) {
            int j2 = idx >> 3, kq = idx & 7;
            float4 v = Ug[j2 * 64 + (k0 >> 2) + kq];
            int kb = kq << 2;
            sW[(kb + 0) * 132 + j2] = v.x; sW[(kb + 1) * 132 + j2] = v.y;
            sW[(kb + 2) * 132 + j2] = v.z; sW[(kb + 3) * 132 + j2] = v.w;
        }
        __syncthreads();
#pragma unroll
        for (int kk = 0; kk < 32; kk += 4) {
            float4 a4[4];
#pragma unroll
            for (int i = 0; i < 4; ++i)
                a4[i] = ((const float4*)sA)[(i0 + i) * 64 + ((k0 + kk) >> 2)];
#pragma unroll
            for (int u = 0; u < 4; ++u) {
                int k = kk + u;
                float4 w = *((const float4*)&sW[k * 132 + j0]);
                const float* wp = (const float*)&w;
#pragma unroll
                for (int i = 0; i < 4; ++i) {
                    float av = ((const float*)&a4[i])[u];
#pragma unroll
                    for (int j = 0; j < 4; ++j)
                        fv[j][i] = fmaf(wp[j], av, fv[j][i]);
                }
            }
        }
    }
#pragma unroll
    for (int j = 0; j < 4; ++j)
#pragma unroll
        for (int i = 0; i < 4; ++i)
            fv[j][i] = sigmoid_(fv[j][i] + wf[j][i]);
    __syncthreads();
    float hs[4][4];
#pragma unroll
    for (int i = 0; i < 4; ++i) {
        float4* row = (float4*)&sA[(i0 + i) * 256];
        float4 c0 = row[jq], c1 = row[32 + jq];
        hs[0][i] = c0.x + c1.x; hs[1][i] = c0.y + c1.y;
        hs[2][i] = c0.z + c1.z; hs[3][i] = c0.w + c1.w;
        c0.x *= fv[0][i]; c0.y *= fv[1][i]; c0.z *= fv[2][i]; c0.w *= fv[3][i];
        c1.x *= fv[0][i]; c1.y *= fv[1][i]; c1.z *= fv[2][i]; c1.w *= fv[3][i];
        row[jq] = c0; row[32 + jq] = c1;
    }
    float cv[4][4];
#pragma unroll
    for (int j = 0; j < 4; ++j)
#pragma unroll
        for (int i = 0; i < 4; ++i) cv[j][i] = 0.f;
    for (int k0 = 0; k0 < 256; k0 += 32) {
        __syncthreads();
        const float4* Ug = (const float4*)Uhc;
        for (int idx = tid; idx < 128 * 8; idx += NT) {
            int j2 = idx >> 3, kq = idx & 7;
            float4 v = Ug[j2 * 64 + (k0 >> 2) + kq];
            int kb = kq << 2;
            sW[(kb + 0) * 132 + j2] = v.x; sW[(kb + 1) * 132 + j2] = v.y;
            sW[(kb + 2) * 132 + j2] = v.z; sW[(kb + 3) * 132 + j2] = v.w;
        }
        __syncthreads();
#pragma unroll
        for (int kk = 0; kk < 32; kk += 4) {
            float4 a4[4];
#pragma unroll
            for (int i = 0; i < 4; ++i)
                a4[i] = ((const float4*)sA)[(i0 + i) * 64 + ((k0 + kk) >> 2)];
#pragma unroll
            for (int u = 0; u < 4; ++u) {
                int k = kk + u;
                float4 w = *((const float4*)&sW[k * 132 + j0]);
                const float* wp = (const float*)&w;
#pragma unroll
                for (int i = 0; i < 4; ++i) {
                    float av = ((const float*)&a4[i])[u];
#pragma unroll
                    for (int j = 0; j < 4; ++j)
                        cv[j][i] = fmaf(wp[j], av, cv[j][i]);
                }
            }
        }
    }
#pragma unroll
    for (int i = 0; i < 4; ++i) {
        if (i0 + i < nb) {
            float4 o; float* op = (float*)&o;
#pragma unroll
            for (int j = 0; j < 4; ++j) {
                float t = tanhf(cv[j][i] + whc[j][i]);
                op[j] = fv[j][i] * hs[j][i] + (1.0f - fv[j][i]) * t;
            }
            *(float4*)&h[((size_t)(s0 + i0 + i)) * 128 + j0] = o;
        }
    }
}

// =================== launcher ===================

extern "C" void kernel_launch(void* const* d_in, const int* in_sizes, int n_in,
                              void* d_out, int out_size, void* d_ws, size_t ws_size,
                              hipStream_t stream)
{
    (void)in_sizes; (void)n_in; (void)out_size;
    const float* x   = (const float*)d_in[0];
    const float* Ww  = (const float*)d_in[1];
    const float* Wb  = (const float*)d_in[2];
    const float* Uf  = (const float*)d_in[3];
    const float* Uhc = (const float*)d_in[4];
    float* h = (float*)d_out;
    const int depth = 18;

    if (ws_size >= WS_BYTES) {
        float* ws = (float*)d_ws;
        prep_pack<<<544, NT, 0, stream>>>(Ww, Uf, Uhc, ws);
        wx_mfma4<<<2048, 512, 0, stream>>>(x, ws, Wb, ws, h);
        for (int lvl = 16; lvl >= 12; --lvl)                     // big levels: A-in-reg MFMA
            lvl_reg<<<1 << (lvl - 6), 512, 0, stream>>>(ws, h, (1 << lvl) - 1);
        for (int lvl = 11; lvl >= 6; --lvl) {                    // small levels: fp32, low latency
            int start = (1 << lvl) - 1;
            int size  = 1 << lvl;
            level_kernel<<<(size + B_NB - 1) / B_NB, NT, 0, stream>>>(ws, h, start, size);
        }
        tail_kernel<<<1, NT, 0, stream>>>(ws, h);
    } else {
        {
            int lvl = depth - 1;
            int start = (1 << lvl) - 1, size = 1 << lvl;
            fb_leaf<<<(size + 31) / 32, NT, 0, stream>>>(x, Ww, Wb, h, start, size);
        }
        for (int lvl = depth - 2; lvl >= 0; --lvl) {
            int start = (1 << lvl) - 1, size = 1 << lvl;
            fb_internal<<<(size + 31) / 32, NT, 0, stream>>>(x, Ww, Wb, Uf, Uhc, h, start, size);
        }
    }
}